// Round 4
// baseline (1049.533 us; speedup 1.0000x reference)
//
#include <hip/hip_runtime.h>
#include <hip/hip_bf16.h>

#define NA 4096
#define NP 49152

// ---------------- ws layout (float-element offsets) ----------------
constexpr int WS_Y     = 0;                    // 512*25 quadrature sph
constexpr int WS_G     = 12800;                // 5625 Gaunt tensor (i*9+j)*25+k
constexpr int WS_NATT  = WS_G + 5632;          // int
constexpr int WS_ATTW  = WS_NATT + 8;          // 1024 floats
constexpr int WS_ATTIJ = WS_ATTW + 1024;       // 1024 ints, sorted by k
constexpr int WS_TDOFS = WS_ATTIJ + 1024;      // 16 ints
constexpr int WS_TDW   = WS_TDOFS + 16;        // 512 floats
constexpr int WS_TDIJ  = WS_TDW + 512;         // 512 ints
constexpr int WS_AOFS  = WS_TDIJ + 512;        // 32 ints (attention per-k offsets)
constexpr int WS_SH    = WS_AOFS + 32;         // NP*9
constexpr int WS_RB    = WS_SH + NP*9;         // NP*16
constexpr int WS_S     = WS_RB + NP*16;        // NP scores
constexpr int WS_CCNT  = WS_S + NP;            // NA ints (csr counts)
constexpr int WS_COFF  = WS_CCNT + NA;         // NA+1 ints (csr offsets)
constexpr int WS_CCUR  = WS_COFF + NA + 8;     // NA ints (fill cursors)
constexpr int WS_CLST  = WS_CCUR + NA;         // NP ints (pair ids sorted by dst)
constexpr int WS_XA    = WS_CLST + NP;         // NA*400: x (atom features)
constexpr int WS_XQ    = WS_XA + NA*400;       // NA*400: q, then reused as agg
constexpr int WS_XK    = WS_XQ + NA*400;
constexpr int WS_XV    = WS_XK + NA*400;
constexpr int WS_END   = WS_XV + NA*400;       // ~38.2 MB

// Gauss-Legendre 16-point nodes/weights.
__device__ const float  GLX[16] = {
  -0.98940093499164993f, -0.94457502307323258f, -0.86563120238783174f, -0.75540440835500303f,
  -0.61787624440264375f, -0.45801677765722739f, -0.28160355077925891f, -0.09501250983763744f,
   0.09501250983763744f,  0.28160355077925891f,  0.45801677765722739f,  0.61787624440264375f,
   0.75540440835500303f,  0.86563120238783174f,  0.94457502307323258f,  0.98940093499164993f };
__device__ const double GLW[16] = {
  0.02715245941175409, 0.06225352393864789, 0.09515851168249278, 0.12462897125553387,
  0.14959598881657673, 0.16915651939500254, 0.18260341504492359, 0.18945061045506850,
  0.18945061045506850, 0.18260341504492359, 0.16915651939500254, 0.14959598881657673,
  0.12462897125553387, 0.09515851168249278, 0.06225352393864789, 0.02715245941175409 };

#define PI_D 3.14159265358979323846

__device__ __forceinline__ float scrub(float v){
  if(!(v == v)) return 0.f;
  return fminf(fmaxf(v, -1e30f), 1e30f);
}

// full real spherical harmonics, lmax=4
__device__ void real_sph25(float ct, float phi, float* Y){
  float st = sqrtf(fmaxf(0.f, 1.f - ct*ct));
  float P[5][5];
  P[0][0] = 1.f;
  #pragma unroll
  for(int m=1;m<=4;m++) P[m][m] = -(2.f*m - 1.f)*st*P[m-1][m-1];
  #pragma unroll
  for(int m=0;m<4;m++) P[m+1][m] = (2.f*m + 1.f)*ct*P[m][m];
  #pragma unroll
  for(int m=0;m<=4;m++){
    #pragma unroll
    for(int l=m+2;l<=4;l++)
      P[l][m] = ((2.f*l - 1.f)*ct*P[l-1][m] - (float)(l+m-1)*P[l-2][m]) / (float)(l-m);
  }
  const double fact[9] = {1,1,2,6,24,120,720,5040,40320};
  int idx = 0;
  #pragma unroll
  for(int l=0;l<=4;l++){
    #pragma unroll
    for(int m=-l;m<=l;m++){
      int ma = (m < 0) ? -m : m;
      float Nn = (float)sqrt((2*l+1)/(4.0*PI_D)*fact[l-ma]/fact[l+ma]);
      float cs = (ma & 1) ? -1.f : 1.f;
      float v;
      if(m == 0)      v = Nn * P[l][0];
      else if(m > 0)  v = 1.4142135623730951f * Nn * cs * cosf(ma*phi) * P[l][ma];
      else            v = 1.4142135623730951f * Nn * cs * sinf(ma*phi) * P[l][ma];
      Y[idx++] = v;
    }
  }
}

__global__ void kq_Y(float* ws){
  int g = blockIdx.x*256 + threadIdx.x;
  if(g >= 512) return;
  float ct  = GLX[g >> 5];
  float phi = (float)((g & 31) * (2.0*PI_D/32.0));
  float Y[25];
  real_sph25(ct, phi, Y);
  #pragma unroll
  for(int i=0;i<25;i++) ws[WS_Y + g*25 + i] = Y[i];
}

__global__ void kq_G(float* ws){
  int t = blockIdx.x*256 + threadIdx.x;
  if(t >= 5625) return;
  int k = t % 25, j = (t/25) % 9, i = t/225;
  const float* Y = ws + WS_Y;
  double acc = 0.0;
  for(int g=0; g<512; g++){
    double w = GLW[g >> 5] * (2.0*PI_D/32.0);
    acc += w * (double)Y[g*25+i] * (double)Y[g*25+j] * (double)Y[g*25+k];
  }
  if(fabs(acc) < 1e-6) acc = 0.0;
  ws[WS_G + (i*9+j)*25 + k] = (float)acc;
}

__global__ void kq_lists(float* ws){
  __shared__ int cA[25], cT[9], oA[26], oT[10];
  int t = threadIdx.x;
  const float* G = ws + WS_G;
  if(t < 25){ int c=0; for(int i=0;i<25;i++) for(int j=0;j<9;j++) if(G[(i*9+j)*25+t] != 0.f) c++; cA[t]=c; }
  if(t < 9){  int c=0; for(int i=0;i<9;i++)  for(int j=0;j<9;j++) if(G[(i*9+j)*25+t] != 0.f) c++; cT[t]=c; }
  __syncthreads();
  if(t == 0){
    int s=0; for(int k=0;k<25;k++){ oA[k]=s; s+=cA[k]; } oA[25]=s;
    ((int*)ws)[WS_NATT] = s;
    s=0; for(int k=0;k<9;k++){ oT[k]=s; s+=cT[k]; } oT[9]=s;
  }
  __syncthreads();
  float* attw = ws + WS_ATTW; int* attij = (int*)ws + WS_ATTIJ;
  int* aofs = (int*)ws + WS_AOFS;
  if(t < 26) aofs[t] = oA[t] < 1024 ? oA[t] : 1024;
  if(t < 25){
    int pos = oA[t];
    for(int i=0;i<25;i++) for(int j=0;j<9;j++){
      float w = G[(i*9+j)*25+t];
      if(w != 0.f && pos < 1024){ attw[pos]=w; attij[pos] = i | (j<<5) | (t<<9); pos++; }
    }
  }
  float* tdw = ws + WS_TDW; int* tdij = (int*)ws + WS_TDIJ; int* tdofs = (int*)ws + WS_TDOFS;
  if(t < 9){
    int pos = oT[t];
    for(int i=0;i<9;i++) for(int j=0;j<9;j++){
      float w = G[(i*9+j)*25+t];
      if(w != 0.f && pos < 512){
        int li = (i==0)?0:(i<4)?1:2, lj = (j==0)?0:(j<4)?1:2;
        tdw[pos]=w; tdij[pos] = i | (j<<5) | (li<<10) | (lj<<12); pos++;
      }
    }
    tdofs[t] = oT[t];
    if(t == 0) tdofs[9] = oT[9];
  }
}

// ---------------- per-pair: sh_b + radial basis ----------------
__global__ void k_pair(const float* disp, float* ws){
  int p = blockIdx.x*256 + threadIdx.x;
  if(p >= NP) return;
  float dx = disp[3*p], dy = disp[3*p+1], dz = disp[3*p+2];
  float r = sqrtf(dx*dx + dy*dy + dz*dz);
  float inv = 1.f / fmaxf(r, 1e-9f);
  float ux = dx*inv, uy = dy*inv, uz = dz*inv;
  float sh[9];
  sh[0] = 0.28209479177387814f;
  sh[1] = 0.4886025119029199f * uy;
  sh[2] = 0.4886025119029199f * uz;
  sh[3] = 0.4886025119029199f * ux;
  sh[4] = 1.0925484305920792f * ux*uy;
  sh[5] = 1.0925484305920792f * uy*uz;
  sh[6] = 0.31539156525252005f * (3.f*uz*uz - 1.f);
  sh[7] = 1.0925484305920792f * ux*uz;
  sh[8] = 0.5462742152960396f * (ux*ux - uy*uy);
  #pragma unroll
  for(int i=0;i<9;i++) ws[WS_SH + p*9 + i] = scrub(sh[i]);
  float mask = (r < 5.f) ? 1.f : 0.f;
  #pragma unroll
  for(int k=1;k<=16;k++){
    float x  = (float)k * r * 0.2f;
    float px = 3.14159265358979323846f * x;
    float s  = (px < 1e-6f) ? 1.f : (sinf(px)/px);
    ws[WS_RB + p*16 + (k-1)] = scrub(s * mask);
  }
}

// ---------------- CSR by dst: count / scan / fill ----------------
__global__ void k_cnt(const int* nbr, float* ws){
  int p = blockIdx.x*256 + threadIdx.x;
  if(p >= NP) return;
  atomicAdd((int*)ws + WS_CCNT + nbr[2*p], 1);
}

__global__ __launch_bounds__(1024) void k_scan(float* ws){
  __shared__ int part[1024];
  int t = threadIdx.x;
  const int* cnt = (const int*)ws + WS_CCNT;
  int v0 = cnt[4*t], v1 = cnt[4*t+1], v2 = cnt[4*t+2], v3 = cnt[4*t+3];
  part[t] = v0+v1+v2+v3;
  __syncthreads();
  for(int o=1; o<1024; o<<=1){
    int x = (t >= o) ? part[t-o] : 0;
    __syncthreads();
    part[t] += x;
    __syncthreads();
  }
  int base = (t > 0) ? part[t-1] : 0;
  int* offp = (int*)ws + WS_COFF;
  int* cur  = (int*)ws + WS_CCUR;
  offp[4*t]   = base;          cur[4*t]   = base;
  offp[4*t+1] = base+v0;       cur[4*t+1] = base+v0;
  offp[4*t+2] = base+v0+v1;    cur[4*t+2] = base+v0+v1;
  offp[4*t+3] = base+v0+v1+v2; cur[4*t+3] = base+v0+v1+v2;
  if(t == 1023) offp[4096] = part[1023];
}

__global__ void k_fill(const int* nbr, float* ws){
  int p = blockIdx.x*256 + threadIdx.x;
  if(p >= NP) return;
  int d = nbr[2*p];
  int pos = atomicAdd((int*)ws + WS_CCUR + d, 1);
  ((int*)ws)[WS_CLST + pos] = p;
}

// ---------------- fused TD phase: one block (64 thr) per atom ----------------
// 4 pair-slots x 16 f-lanes; weights staged in LDS; acc in regs; no atomics.
__global__ __launch_bounds__(64) void k_td_fused(const int* aZ, const int* nbr,
    const float* Wrad, const float* W1, const float* W2, const float* W3, float* ws){
  __shared__ float Wsh[2304];        // W1 | W2 | W3 (3*256 each)
  __shared__ float sh_s[4][9];
  __shared__ float y0_s[4][16];
  __shared__ float tp_s[4][9][17];
  int a = blockIdx.x;
  int lane = threadIdx.x, slot = lane >> 4, g = lane & 15;
  for(int t=lane; t<768; t+=64){
    Wsh[t] = W1[t]; Wsh[768+t] = W2[t]; Wsh[1536+t] = W3[t];
  }
  const int* coff = (const int*)ws + WS_COFF;
  const int* clst = (const int*)ws + WS_CLST;
  int off0 = coff[a], n = coff[a+1] - off0;
  float acc9[9] = {0,0,0,0,0,0,0,0,0};
  const float* tdw = ws + WS_TDW;
  const int* tdij  = (const int*)ws + WS_TDIJ;
  const int* tdofs = (const int*)ws + WS_TDOFS;
  __syncthreads();
  int rounds = (n + 3) >> 2;
  for(int r=0; r<rounds; r++){
    int t = r*4 + slot;
    bool act = t < n;
    int p = clst[off0 + (act ? t : 0)];
    int src = nbr[2*p+1];
    int Zj = aZ[src];
    if(g < 9) sh_s[slot][g] = act ? ws[WS_SH + p*9 + g] : 0.f;
    float rbv = act ? ws[WS_RB + p*16 + g] : 0.f;
    float y0 = 0.f;
    #pragma unroll
    for(int k=0;k<16;k++){
      float rk = __shfl(rbv, k, 16);
      y0 += rk * Wrad[(Zj*16+k)*16+g];
    }
    y0_s[slot][g] = y0;
    __syncthreads();
    float A1[3] = {0,0,0}, A2[3] = {0,0,0};
    #pragma unroll
    for(int fp=0; fp<16; fp++){
      float v = y0_s[slot][fp];
      #pragma unroll
      for(int d=0; d<3; d++){
        A1[d] += v * Wsh[(d*16+fp)*16+g];
        A2[d] += v * Wsh[768+(d*16+fp)*16+g];
      }
    }
    #pragma unroll
    for(int k=0;k<9;k++){
      float acc = 0.f;
      int e1 = tdofs[k+1];
      for(int e=tdofs[k]; e<e1; e++){
        float w = tdw[e]; int meta = tdij[e];
        int i = meta & 31, j = (meta>>5) & 15, li = (meta>>10) & 3, lj = (meta>>12) & 3;
        float a1 = (li==0)?A1[0]:(li==1)?A1[1]:A1[2];
        float a2 = (lj==0)?A2[0]:(lj==1)?A2[1]:A2[2];
        acc += w * sh_s[slot][i] * sh_s[slot][j] * a1 * a2;
      }
      tp_s[slot][k][g] = acc;
    }
    __syncthreads();
    if(act){
      #pragma unroll
      for(int k=0;k<9;k++){
        int d = (k==0)?0:(k<4)?1:2;
        float acc = 0.f;
        #pragma unroll
        for(int f2=0;f2<16;f2++) acc += tp_s[slot][k][f2] * Wsh[1536+(d*16+f2)*16+g];
        acc9[k] += acc;
      }
    }
    __syncthreads();
  }
  // reduce across the 4 slots (all within one wave)
  #pragma unroll
  for(int k=0;k<9;k++){
    acc9[k] += __shfl_xor(acc9[k], 16);
    acc9[k] += __shfl_xor(acc9[k], 32);
  }
  if(slot == 0){
    float invc = 1.f / fmaxf((float)n, 1.f);
    #pragma unroll
    for(int k=0;k<9;k++)  ws[WS_XA + a*400 + k*16 + g] = scrub(acc9[k]*invc);
    #pragma unroll
    for(int k=9;k<25;k++) ws[WS_XA + a*400 + k*16 + g] = 0.f;
  }
}

// ---------------- per-atom Q/K/V pdense (16 atoms x 16 lanes) ----------------
__global__ __launch_bounds__(256) void k_qkv(const float* Wq,
    const float* Wk, const float* Wv, float* ws){
  int tid = threadIdx.x, al = tid >> 4, g = tid & 15;
  int a = blockIdx.x*16 + al;
  const float* x = ws + WS_XA + a*400;
  int i = 0;
  #pragma unroll
  for(int l=0;l<5;l++){
    float wq[16], wk[16], wv[16];
    #pragma unroll
    for(int f2=0;f2<16;f2++){
      wq[f2] = Wq[(l*16+f2)*16+g];
      wk[f2] = Wk[(l*16+f2)*16+g];
      wv[f2] = Wv[(l*16+f2)*16+g];
    }
    for(int mi=0; mi<2*l+1; mi++, i++){
      float q=0.f, k2=0.f, v2=0.f;
      #pragma unroll
      for(int f2=0;f2<16;f2++){
        float xv = x[i*16+f2];
        q += xv*wq[f2]; k2 += xv*wk[f2]; v2 += xv*wv[f2];
      }
      ws[WS_XQ + a*400 + i*16 + g] = q;
      ws[WS_XK + a*400 + i*16 + g] = k2;
      ws[WS_XV + a*400 + i*16 + g] = v2;
    }
  }
}

// Conflict-free per-slot M build: M[i,k] = sum_j G[i,j,k]*sh[j]; lane g owns
// rows k=g,g+16. All lanes of a block participate (barrier-safe).
#define M_BUILD4() \
  do { \
    float4* M4 = (float4*)&Ml[slot][0]; \
    for(int t0=g; t0<175; t0+=16) M4[t0] = make_float4(0.f,0.f,0.f,0.f); \
    if(g < 9) sh_s[slot][g] = act ? ws[WS_SH + p*9 + g] : 0.f; \
    __syncthreads(); \
    const float* attw = ws + WS_ATTW; \
    const int* attij  = (const int*)ws + WS_ATTIJ; \
    const int* aofs   = (const int*)ws + WS_AOFS; \
    for(int kr=g; kr<25; kr+=16){ \
      float* Mrow = &Ml[slot][kr*28]; \
      int e1 = aofs[kr+1]; \
      for(int e=aofs[kr]; e<e1; e++){ \
        int meta = attij[e]; \
        Mrow[meta & 31] += attw[e] * sh_s[slot][(meta>>5) & 15]; \
      } \
    } \
    __syncthreads(); \
  } while(0)

// ---------------- per-atom attention scores ----------------
__global__ __launch_bounds__(64) void k_s_fused(const int* nbr, const float* Wb, float* ws){
  __shared__ __align__(16) float Ml[4][25*28];
  __shared__ float sh_s[4][9];
  int a = blockIdx.x;
  int lane = threadIdx.x, slot = lane >> 4, g = lane & 15;
  const int* coff = (const int*)ws + WS_COFF;
  const int* clst = (const int*)ws + WS_CLST;
  int off0 = coff[a], n = coff[a+1] - off0;
  if(n == 0) return;
  float wb16[16];
  #pragma unroll
  for(int k=0;k<16;k++) wb16[k] = Wb[k*16+g];
  float q_r[25];
  #pragma unroll
  for(int i=0;i<25;i++) q_r[i] = ws[WS_XQ + a*400 + i*16 + g];
  int rounds = (n + 3) >> 2;
  for(int r=0; r<rounds; r++){
    int t = r*4 + slot;
    bool act = t < n;
    int p = clst[off0 + (act ? t : 0)];
    M_BUILD4();
    int src = nbr[2*p+1];
    float xk_r[25];
    #pragma unroll
    for(int i=0;i<25;i++) xk_r[i] = ws[WS_XK + src*400 + i*16 + g];
    float rbv = ws[WS_RB + p*16 + g];
    float wbf = 0.f;
    #pragma unroll
    for(int k=0;k<16;k++) wbf += __shfl(rbv, k, 16) * wb16[k];
    float sacc = 0.f;
    #pragma unroll
    for(int k=0;k<25;k++){
      const float* Mr = &Ml[slot][k*28];
      float kf = 0.f;
      #pragma unroll
      for(int c=0;c<6;c++){
        float4 m4 = *(const float4*)(Mr + 4*c);
        kf += m4.x*xk_r[4*c] + m4.y*xk_r[4*c+1] + m4.z*xk_r[4*c+2] + m4.w*xk_r[4*c+3];
      }
      kf += Mr[24]*xk_r[24];
      sacc += q_r[k]*kf;
    }
    float sl = wbf * sacc;
    #pragma unroll
    for(int off=1; off<16; off<<=1) sl += __shfl_xor(sl, off, 16);
    if(act && g == 0) ws[WS_S + p] = scrub(sl * 0.05f);
    __syncthreads();
  }
}

// ---------------- per-atom fused softmax + aggregation (no atomics) --------
// writes agg into the (dead) XQ buffer.
__global__ __launch_bounds__(64) void k_agg_fused(const int* nbr, const float* Wb, float* ws){
  __shared__ __align__(16) float Ml[4][25*28];
  __shared__ float sh_s[4][9];
  int a = blockIdx.x;
  int lane = threadIdx.x, slot = lane >> 4, g = lane & 15;
  const int* coff = (const int*)ws + WS_COFF;
  const int* clst = (const int*)ws + WS_CLST;
  int off0 = coff[a], n = coff[a+1] - off0;
  // segment softmax prologue (wave-wide)
  float mx = -1e30f;
  for(int t=lane; t<n; t+=64) mx = fmaxf(mx, ws[WS_S + clst[off0+t]]);
  #pragma unroll
  for(int off=1; off<64; off<<=1) mx = fmaxf(mx, __shfl_xor(mx, off));
  float den = 0.f;
  for(int t=lane; t<n; t+=64) den += expf(fminf(ws[WS_S + clst[off0+t]] - mx, 0.f));
  #pragma unroll
  for(int off=1; off<64; off<<=1) den += __shfl_xor(den, off);
  float inv_den = 1.f / (den + 1e-9f);
  float wb16[16];
  #pragma unroll
  for(int k=0;k<16;k++) wb16[k] = Wb[k*16+g];
  float acc[25];
  #pragma unroll
  for(int i=0;i<25;i++) acc[i] = 0.f;
  int rounds = (n + 3) >> 2;
  for(int r=0; r<rounds; r++){
    int t = r*4 + slot;
    bool act = t < n;
    int p = clst[off0 + (act ? t : 0)];
    M_BUILD4();
    int src = nbr[2*p+1];
    float xv_r[25];
    #pragma unroll
    for(int i=0;i<25;i++) xv_r[i] = ws[WS_XV + src*400 + i*16 + g];
    float rbv = ws[WS_RB + p*16 + g];
    float wbf = 0.f;
    #pragma unroll
    for(int k=0;k<16;k++) wbf += __shfl(rbv, k, 16) * wb16[k];
    float alpha = act ? expf(fminf(ws[WS_S + p] - mx, 0.f)) * inv_den : 0.f;
    float aw = alpha * wbf;
    #pragma unroll
    for(int k=0;k<25;k++){
      const float* Mr = &Ml[slot][k*28];
      float vf = 0.f;
      #pragma unroll
      for(int c=0;c<6;c++){
        float4 m4 = *(const float4*)(Mr + 4*c);
        vf += m4.x*xv_r[4*c] + m4.y*xv_r[4*c+1] + m4.z*xv_r[4*c+2] + m4.w*xv_r[4*c+3];
      }
      vf += Mr[24]*xv_r[24];
      acc[k] += aw*vf;
    }
    __syncthreads();
  }
  #pragma unroll
  for(int k=0;k<25;k++){
    acc[k] += __shfl_xor(acc[k], 16);
    acc[k] += __shfl_xor(acc[k], 32);
  }
  if(slot == 0){
    #pragma unroll
    for(int k=0;k<25;k++) ws[WS_XQ + a*400 + k*16 + g] = scrub(acc[k]);
  }
}

// ---------------- output pdense + bias: reads XQ(agg), writes XA(x) --------
__global__ __launch_bounds__(256) void k_o(const float* Wo, const float* bo, float* ws){
  int tid = threadIdx.x, al = tid >> 4, g = tid & 15;
  int a = blockIdx.x*16 + al;
  const float* agg = ws + WS_XQ + a*400;
  int i = 0;
  #pragma unroll
  for(int l=0;l<5;l++){
    float wo[16];
    #pragma unroll
    for(int f2=0;f2<16;f2++) wo[f2] = Wo[(l*16+f2)*16+g];
    for(int mi=0; mi<2*l+1; mi++, i++){
      float acc = 0.f;
      #pragma unroll
      for(int f2=0;f2<16;f2++) acc += agg[i*16+f2]*wo[f2];
      if(i == 0) acc += bo[g];
      ws[WS_XA + a*400 + i*16 + g] = scrub(acc);
    }
  }
}

// ---------------- embedding residual + f32 output ----------------
__global__ void k_resout(const int* aZ, const float* emb, const float* Wemb,
                         const float* bemb, const float* ws, float* out){
  int idx = blockIdx.x*256 + threadIdx.x;
  if(idx >= NA*400) return;
  int a = idx/400, r2 = idx%400, i = r2>>4, f = r2&15;
  float v = ws[WS_XA + idx];
  if(i == 0){
    int Z = aZ[a];
    float res = bemb[f];
    #pragma unroll
    for(int e2=0;e2<32;e2++) res += emb[Z*32+e2] * Wemb[e2*16+f];
    v += res;
  }
  out[idx] = scrub(v);
}

extern "C" void kernel_launch(void* const* d_in, const int* in_sizes, int n_in,
                              void* d_out, int out_size, void* d_ws, size_t ws_size,
                              hipStream_t stream){
  (void)in_sizes; (void)n_in; (void)out_size;
  if(ws_size < (size_t)WS_END * sizeof(float)) return;
  float* ws = (float*)d_ws;
  const int* aZ  = (const int*)d_in[0];
  const int* nbr = (const int*)d_in[1];
  const float* disp = (const float*)d_in[2];
  const float* Wrad = (const float*)d_in[3];
  const float* emb  = (const float*)d_in[4];
  const float* Wemb = (const float*)d_in[5];
  const float* bemb = (const float*)d_in[6];
  const float* W1   = (const float*)d_in[7];
  const float* W2   = (const float*)d_in[8];
  const float* W3   = (const float*)d_in[9];

  kq_Y<<<2,256,0,stream>>>(ws);
  kq_G<<<22,256,0,stream>>>(ws);
  kq_lists<<<1,64,0,stream>>>(ws);
  k_pair<<<192,256,0,stream>>>(disp, ws);
  hipMemsetAsync(ws + WS_CCNT, 0, NA*sizeof(int), stream);
  k_cnt<<<192,256,0,stream>>>(nbr, ws);
  k_scan<<<1,1024,0,stream>>>(ws);
  k_fill<<<192,256,0,stream>>>(nbr, ws);
  k_td_fused<<<NA,64,0,stream>>>(aZ, nbr, Wrad, W1, W2, W3, ws);

  for(int l=0;l<2;l++){
    const float* Wb = (const float*)d_in[10+6*l];
    const float* Wq = (const float*)d_in[11+6*l];
    const float* Wk = (const float*)d_in[12+6*l];
    const float* Wv = (const float*)d_in[13+6*l];
    const float* Wo = (const float*)d_in[14+6*l];
    const float* bo = (const float*)d_in[15+6*l];
    k_qkv<<<256,256,0,stream>>>(Wq, Wk, Wv, ws);
    k_s_fused<<<NA,64,0,stream>>>(nbr, Wb, ws);
    k_agg_fused<<<NA,64,0,stream>>>(nbr, Wb, ws);
    k_o<<<256,256,0,stream>>>(Wo, bo, ws);
  }
  k_resout<<<6400,256,0,stream>>>(aZ, emb, Wemb, bemb, ws, (float*)d_out);
}

// Round 5
// 675.983 us; speedup vs baseline: 1.5526x; 1.5526x over previous
//
#include <hip/hip_runtime.h>
#include <hip/hip_bf16.h>

#define NA 4096
#define NP 49152

// ---------------- ws layout (float-element offsets) ----------------
constexpr int WS_Y     = 0;                    // 512*25 quadrature sph
constexpr int WS_G     = 12800;                // 5625 Gaunt tensor (i*9+j)*25+k
constexpr int WS_NATT  = WS_G + 5632;          // int
constexpr int WS_ATTW  = WS_NATT + 8;          // 1024 floats
constexpr int WS_ATTIJ = WS_ATTW + 1024;       // 1024 ints, sorted by k
constexpr int WS_TDOFS = WS_ATTIJ + 1024;      // 16 ints
constexpr int WS_TDW   = WS_TDOFS + 16;        // 512 floats
constexpr int WS_TDIJ  = WS_TDW + 512;         // 512 ints
constexpr int WS_AOFS  = WS_TDIJ + 512;        // 32 ints
constexpr int WS_SH    = WS_AOFS + 32;         // NP*9
constexpr int WS_RB    = WS_SH + NP*9;         // NP*16
constexpr int WS_S     = WS_RB + NP*16;        // NP scores
constexpr int WS_MX    = WS_S + NP;            // NA segment max
constexpr int WS_ID    = WS_MX + NA;           // NA 1/den
constexpr int WS_CCNT  = WS_ID + NA;           // NA ints
constexpr int WS_COFF  = WS_CCNT + NA;         // NA+1 ints
constexpr int WS_CCUR  = WS_COFF + NA + 8;     // NA ints
constexpr int WS_CLST  = WS_CCUR + NA;         // NP ints
constexpr int WS_SUMS  = WS_CLST + NP;         // NA*144
constexpr int WS_CNT   = WS_SUMS + NA*144;     // NA
constexpr int WS_XA    = WS_CNT + NA;          // NA*400 x
constexpr int WS_XQ    = WS_XA + NA*400;       // NA*400 q, reused as agg
constexpr int WS_XK    = WS_XQ + NA*400;
constexpr int WS_XV    = WS_XK + NA*400;
constexpr int WS_BASE_END = WS_XV + NA*400;    // ~34.2 MB
constexpr int WS_PVF   = WS_BASE_END;          // NP*400 per-pair vf scratch (Plan A)
constexpr long long WS_PLANA_END = (long long)WS_PVF + (long long)NP*400; // ~112.8 MB

__device__ const float  GLX[16] = {
  -0.98940093499164993f, -0.94457502307323258f, -0.86563120238783174f, -0.75540440835500303f,
  -0.61787624440264375f, -0.45801677765722739f, -0.28160355077925891f, -0.09501250983763744f,
   0.09501250983763744f,  0.28160355077925891f,  0.45801677765722739f,  0.61787624440264375f,
   0.75540440835500303f,  0.86563120238783174f,  0.94457502307323258f,  0.98940093499164993f };
__device__ const double GLW[16] = {
  0.02715245941175409, 0.06225352393864789, 0.09515851168249278, 0.12462897125553387,
  0.14959598881657673, 0.16915651939500254, 0.18260341504492359, 0.18945061045506850,
  0.18945061045506850, 0.18260341504492359, 0.16915651939500254, 0.14959598881657673,
  0.12462897125553387, 0.09515851168249278, 0.06225352393864789, 0.02715245941175409 };

#define PI_D 3.14159265358979323846

__device__ __forceinline__ float scrub(float v){
  if(!(v == v)) return 0.f;
  return fminf(fmaxf(v, -1e30f), 1e30f);
}

// full real spherical harmonics, lmax=4
__device__ void real_sph25(float ct, float phi, float* Y){
  float st = sqrtf(fmaxf(0.f, 1.f - ct*ct));
  float P[5][5];
  P[0][0] = 1.f;
  #pragma unroll
  for(int m=1;m<=4;m++) P[m][m] = -(2.f*m - 1.f)*st*P[m-1][m-1];
  #pragma unroll
  for(int m=0;m<4;m++) P[m+1][m] = (2.f*m + 1.f)*ct*P[m][m];
  #pragma unroll
  for(int m=0;m<=4;m++){
    #pragma unroll
    for(int l=m+2;l<=4;l++)
      P[l][m] = ((2.f*l - 1.f)*ct*P[l-1][m] - (float)(l+m-1)*P[l-2][m]) / (float)(l-m);
  }
  const double fact[9] = {1,1,2,6,24,120,720,5040,40320};
  int idx = 0;
  #pragma unroll
  for(int l=0;l<=4;l++){
    #pragma unroll
    for(int m=-l;m<=l;m++){
      int ma = (m < 0) ? -m : m;
      float Nn = (float)sqrt((2*l+1)/(4.0*PI_D)*fact[l-ma]/fact[l+ma]);
      float cs = (ma & 1) ? -1.f : 1.f;
      float v;
      if(m == 0)      v = Nn * P[l][0];
      else if(m > 0)  v = 1.4142135623730951f * Nn * cs * cosf(ma*phi) * P[l][ma];
      else            v = 1.4142135623730951f * Nn * cs * sinf(ma*phi) * P[l][ma];
      Y[idx++] = v;
    }
  }
}

__global__ void kq_Y(float* ws){
  int g = blockIdx.x*256 + threadIdx.x;
  if(g >= 512) return;
  float ct  = GLX[g >> 5];
  float phi = (float)((g & 31) * (2.0*PI_D/32.0));
  float Y[25];
  real_sph25(ct, phi, Y);
  #pragma unroll
  for(int i=0;i<25;i++) ws[WS_Y + g*25 + i] = Y[i];
}

// G via LDS-staged Y (kills global-load latency in the 512-iter loop)
__global__ __launch_bounds__(256) void kq_G(float* ws){
  __shared__ float Ysh[12800];
  int tid = threadIdx.x;
  for(int t=tid; t<12800; t+=256) Ysh[t] = ws[WS_Y + t];
  __syncthreads();
  int t = blockIdx.x*256 + tid;
  if(t >= 5625) return;
  int k = t % 25, j = (t/25) % 9, i = t/225;
  double acc = 0.0;
  #pragma unroll 4
  for(int g=0; g<512; g++){
    double w = GLW[g >> 5] * (2.0*PI_D/32.0);
    acc += w * (double)Ysh[g*25+i] * (double)Ysh[g*25+j] * (double)Ysh[g*25+k];
  }
  if(fabs(acc) < 1e-6) acc = 0.0;
  ws[WS_G + (i*9+j)*25 + k] = (float)acc;
}

__global__ void kq_lists(float* ws){
  __shared__ int cA[25], cT[9], oA[26], oT[10];
  int t = threadIdx.x;
  const float* G = ws + WS_G;
  if(t < 25){ int c=0; for(int i=0;i<25;i++) for(int j=0;j<9;j++) if(G[(i*9+j)*25+t] != 0.f) c++; cA[t]=c; }
  if(t < 9){  int c=0; for(int i=0;i<9;i++)  for(int j=0;j<9;j++) if(G[(i*9+j)*25+t] != 0.f) c++; cT[t]=c; }
  __syncthreads();
  if(t == 0){
    int s=0; for(int k=0;k<25;k++){ oA[k]=s; s+=cA[k]; } oA[25]=s;
    ((int*)ws)[WS_NATT] = s;
    s=0; for(int k=0;k<9;k++){ oT[k]=s; s+=cT[k]; } oT[9]=s;
  }
  __syncthreads();
  float* attw = ws + WS_ATTW; int* attij = (int*)ws + WS_ATTIJ;
  int* aofs = (int*)ws + WS_AOFS;
  if(t < 26) aofs[t] = oA[t] < 1024 ? oA[t] : 1024;
  if(t < 25){
    int pos = oA[t];
    for(int i=0;i<25;i++) for(int j=0;j<9;j++){
      float w = G[(i*9+j)*25+t];
      if(w != 0.f && pos < 1024){ attw[pos]=w; attij[pos] = i | (j<<5) | (t<<9); pos++; }
    }
  }
  float* tdw = ws + WS_TDW; int* tdij = (int*)ws + WS_TDIJ; int* tdofs = (int*)ws + WS_TDOFS;
  if(t < 9){
    int pos = oT[t];
    for(int i=0;i<9;i++) for(int j=0;j<9;j++){
      float w = G[(i*9+j)*25+t];
      if(w != 0.f && pos < 512){
        int li = (i==0)?0:(i<4)?1:2, lj = (j==0)?0:(j<4)?1:2;
        tdw[pos]=w; tdij[pos] = i | (j<<5) | (li<<10) | (lj<<12); pos++;
      }
    }
    tdofs[t] = oT[t];
    if(t == 0) tdofs[9] = oT[9];
  }
}

__global__ void k_pair(const float* disp, float* ws){
  int p = blockIdx.x*256 + threadIdx.x;
  if(p >= NP) return;
  float dx = disp[3*p], dy = disp[3*p+1], dz = disp[3*p+2];
  float r = sqrtf(dx*dx + dy*dy + dz*dz);
  float inv = 1.f / fmaxf(r, 1e-9f);
  float ux = dx*inv, uy = dy*inv, uz = dz*inv;
  float sh[9];
  sh[0] = 0.28209479177387814f;
  sh[1] = 0.4886025119029199f * uy;
  sh[2] = 0.4886025119029199f * uz;
  sh[3] = 0.4886025119029199f * ux;
  sh[4] = 1.0925484305920792f * ux*uy;
  sh[5] = 1.0925484305920792f * uy*uz;
  sh[6] = 0.31539156525252005f * (3.f*uz*uz - 1.f);
  sh[7] = 1.0925484305920792f * ux*uz;
  sh[8] = 0.5462742152960396f * (ux*ux - uy*uy);
  #pragma unroll
  for(int i=0;i<9;i++) ws[WS_SH + p*9 + i] = scrub(sh[i]);
  float mask = (r < 5.f) ? 1.f : 0.f;
  #pragma unroll
  for(int k=1;k<=16;k++){
    float x  = (float)k * r * 0.2f;
    float px = 3.14159265358979323846f * x;
    float s  = (px < 1e-6f) ? 1.f : (sinf(px)/px);
    ws[WS_RB + p*16 + (k-1)] = scrub(s * mask);
  }
}

// ---------------- CSR by dst ----------------
__global__ void k_cnt(const int* nbr, float* ws){
  int p = blockIdx.x*256 + threadIdx.x;
  if(p >= NP) return;
  atomicAdd((int*)ws + WS_CCNT + nbr[2*p], 1);
}

__global__ __launch_bounds__(1024) void k_scan(float* ws){
  __shared__ int part[1024];
  int t = threadIdx.x;
  const int* cnt = (const int*)ws + WS_CCNT;
  int v0 = cnt[4*t], v1 = cnt[4*t+1], v2 = cnt[4*t+2], v3 = cnt[4*t+3];
  part[t] = v0+v1+v2+v3;
  __syncthreads();
  for(int o=1; o<1024; o<<=1){
    int x = (t >= o) ? part[t-o] : 0;
    __syncthreads();
    part[t] += x;
    __syncthreads();
  }
  int base = (t > 0) ? part[t-1] : 0;
  int* offp = (int*)ws + WS_COFF;
  int* cur  = (int*)ws + WS_CCUR;
  offp[4*t]   = base;          cur[4*t]   = base;
  offp[4*t+1] = base+v0;       cur[4*t+1] = base+v0;
  offp[4*t+2] = base+v0+v1;    cur[4*t+2] = base+v0+v1;
  offp[4*t+3] = base+v0+v1+v2; cur[4*t+3] = base+v0+v1+v2;
  if(t == 1023) offp[4096] = part[1023];
}

__global__ void k_fill(const int* nbr, float* ws){
  int p = blockIdx.x*256 + threadIdx.x;
  if(p >= NP) return;
  int d = nbr[2*p];
  int pos = atomicAdd((int*)ws + WS_CCUR + d, 1);
  ((int*)ws)[WS_CLST + pos] = p;
}

// ---------------- TD phase: per-pair (16 pairs x 16 lanes), atomic sums ----
__global__ __launch_bounds__(256) void k_td(const int* aZ, const int* nbr,
    const float* Wrad, const float* W1, const float* W2,
    const float* W3, float* ws){
  __shared__ float sh_s[16][9];
  __shared__ float tp_s[16][9][16];
  int tid = threadIdx.x, pl = tid >> 4, g = tid & 15;
  int p = blockIdx.x*16 + pl;
  int dst = nbr[2*p], src = nbr[2*p+1];
  int Zj = aZ[src];
  if(g < 9) sh_s[pl][g] = ws[WS_SH + p*9 + g];
  float rbv = ws[WS_RB + p*16 + g];
  float y0 = 0.f;
  #pragma unroll
  for(int k=0;k<16;k++){
    float rk = __shfl(rbv, k, 16);
    y0 += rk * Wrad[(Zj*16+k)*16+g];
  }
  float A1[3] = {0,0,0}, A2[3] = {0,0,0};
  #pragma unroll
  for(int fp=0;fp<16;fp++){
    float v = __shfl(y0, fp, 16);
    #pragma unroll
    for(int d=0;d<3;d++){
      A1[d] += v * W1[(d*16+fp)*16+g];
      A2[d] += v * W2[(d*16+fp)*16+g];
    }
  }
  __syncthreads();
  const float* tdw = ws + WS_TDW;
  const int* tdij  = (const int*)ws + WS_TDIJ;
  const int* tdofs = (const int*)ws + WS_TDOFS;
  #pragma unroll
  for(int k=0;k<9;k++){
    float acc = 0.f;
    int e1 = tdofs[k+1];
    for(int e=tdofs[k]; e<e1; e++){
      float w = tdw[e]; int meta = tdij[e];
      int i = meta & 31, j = (meta>>5) & 15, li = (meta>>10) & 3, lj = (meta>>12) & 3;
      float a1 = (li==0)?A1[0]:(li==1)?A1[1]:A1[2];
      float a2 = (lj==0)?A2[0]:(lj==1)?A2[1]:A2[2];
      acc += w * sh_s[pl][i] * sh_s[pl][j] * a1 * a2;
    }
    tp_s[pl][k][g] = acc;
  }
  __syncthreads();
  float* sums = ws + WS_SUMS;
  #pragma unroll
  for(int k=0;k<9;k++){
    int d = (k==0)?0:(k<4)?1:2;
    float acc = 0.f;
    #pragma unroll
    for(int f2=0;f2<16;f2++) acc += tp_s[pl][k][f2] * W3[(d*16+f2)*16+g];
    unsafeAtomicAdd(&sums[dst*144 + k*16 + g], scrub(acc));
  }
  if(g == 0) unsafeAtomicAdd(ws + WS_CNT + dst, 1.f);
}

// ---------------- mean + pad to 25 rows ----------------
__global__ void k_x(float* ws){
  int idx = blockIdx.x*256 + threadIdx.x;
  if(idx >= NA*400) return;
  int a = idx/400, r2 = idx%400, i = r2>>4, f = r2&15;
  float v = 0.f;
  if(i < 9){
    float c = ws[WS_CNT + a];
    v = ws[WS_SUMS + a*144 + i*16 + f] / fmaxf(c, 1.f);
  }
  ws[WS_XA + idx] = scrub(v);
}

// ---------------- per-atom Q/K/V pdense ----------------
__global__ __launch_bounds__(256) void k_qkv(const float* Wq,
    const float* Wk, const float* Wv, float* ws){
  int tid = threadIdx.x, al = tid >> 4, g = tid & 15;
  int a = blockIdx.x*16 + al;
  const float* x = ws + WS_XA + a*400;
  int i = 0;
  #pragma unroll
  for(int l=0;l<5;l++){
    float wq[16], wk[16], wv[16];
    #pragma unroll
    for(int f2=0;f2<16;f2++){
      wq[f2] = Wq[(l*16+f2)*16+g];
      wk[f2] = Wk[(l*16+f2)*16+g];
      wv[f2] = Wv[(l*16+f2)*16+g];
    }
    for(int mi=0; mi<2*l+1; mi++, i++){
      float q=0.f, k2=0.f, v2=0.f;
      #pragma unroll
      for(int f2=0;f2<16;f2++){
        float xv = x[i*16+f2];
        q += xv*wq[f2]; k2 += xv*wk[f2]; v2 += xv*wv[f2];
      }
      ws[WS_XQ + a*400 + i*16 + g] = q;
      ws[WS_XK + a*400 + i*16 + g] = k2;
      ws[WS_XV + a*400 + i*16 + g] = v2;
    }
  }
}

// Conflict-free M build (8 pairs x 16 lanes / 128-thr block)
#define M_BUILD() \
  do { \
    float4* M4 = (float4*)&Ml[0][0]; \
    for(int t0=tid; t0<8*25*7; t0+=128) M4[t0] = make_float4(0.f,0.f,0.f,0.f); \
    if(g < 9) sh_s[pl][g] = ws[WS_SH + p*9 + g]; \
    __syncthreads(); \
    const float* attw = ws + WS_ATTW; \
    const int* attij  = (const int*)ws + WS_ATTIJ; \
    const int* aofs   = (const int*)ws + WS_AOFS; \
    for(int kr=g; kr<25; kr+=16){ \
      float* Mrow = &Ml[pl][kr*28]; \
      int e1 = aofs[kr+1]; \
      for(int e=aofs[kr]; e<e1; e++){ \
        int meta = attij[e]; \
        Mrow[meta & 31] += attw[e] * sh_s[pl][(meta>>5) & 15]; \
      } \
    } \
    __syncthreads(); \
  } while(0)

// ---------------- scores (no atomicMax — k_soft does segment max) ----------
__global__ __launch_bounds__(128) void k_s2(const int* nbr, const float* Wb, float* ws){
  __shared__ __align__(16) float Ml[8][25*28];
  __shared__ float sh_s[8][9];
  int tid = threadIdx.x, pl = tid >> 4, g = tid & 15;
  int p = blockIdx.x*8 + pl;
  M_BUILD();
  int dst = nbr[2*p], src = nbr[2*p+1];
  float q_r[25], xk_r[25];
  #pragma unroll
  for(int i=0;i<25;i++){
    q_r[i]  = ws[WS_XQ + dst*400 + i*16 + g];
    xk_r[i] = ws[WS_XK + src*400 + i*16 + g];
  }
  float wbf = 0.f;
  #pragma unroll
  for(int k=0;k<16;k++) wbf += ws[WS_RB + p*16 + k] * Wb[k*16+g];
  float sacc = 0.f;
  #pragma unroll
  for(int k=0;k<25;k++){
    const float* Mr = &Ml[pl][k*28];
    float kf = 0.f;
    #pragma unroll
    for(int c=0;c<6;c++){
      float4 m4 = *(const float4*)(Mr + 4*c);
      kf += m4.x*xk_r[4*c] + m4.y*xk_r[4*c+1] + m4.z*xk_r[4*c+2] + m4.w*xk_r[4*c+3];
    }
    kf += Mr[24]*xk_r[24];
    sacc += q_r[k]*kf;
  }
  float sl = wbf * sacc;
  #pragma unroll
  for(int off=1; off<16; off<<=1) sl += __shfl_xor(sl, off, 16);
  if(g == 0) ws[WS_S + p] = scrub(sl * 0.05f);
}

// ---------------- per-atom softmax stats (wave per atom, 4 atoms/block) ----
__global__ __launch_bounds__(256) void k_soft(float* ws){
  int a = blockIdx.x*4 + (threadIdx.x >> 6);
  int lane = threadIdx.x & 63;
  const int* coff = (const int*)ws + WS_COFF;
  const int* clst = (const int*)ws + WS_CLST;
  int off0 = coff[a], n = coff[a+1] - off0;
  float mx = -1e30f;
  for(int t=lane; t<n; t+=64) mx = fmaxf(mx, ws[WS_S + clst[off0+t]]);
  #pragma unroll
  for(int off=1; off<64; off<<=1) mx = fmaxf(mx, __shfl_xor(mx, off));
  float den = 0.f;
  for(int t=lane; t<n; t+=64) den += expf(fminf(ws[WS_S + clst[off0+t]] - mx, 0.f));
  #pragma unroll
  for(int off=1; off<64; off<<=1) den += __shfl_xor(den, off);
  if(lane == 0){
    ws[WS_MX + a] = mx;
    ws[WS_ID + a] = 1.f / (den + 1e-9f);
  }
}

// ---------------- aggregation body (shared by both plans) ----------------
template<bool GATHER>
__device__ __forceinline__ void agg_body(const int* nbr, const float* Wb, float* ws,
                                         float (&Ml)[8][25*28], float (&sh_s)[8][9]){
  int tid = threadIdx.x, pl = tid >> 4, g = tid & 15;
  int p = blockIdx.x*8 + pl;
  M_BUILD();
  int dst = nbr[2*p], src = nbr[2*p+1];
  float xv_r[25];
  #pragma unroll
  for(int i=0;i<25;i++) xv_r[i] = ws[WS_XV + src*400 + i*16 + g];
  float wbf = 0.f;
  #pragma unroll
  for(int k=0;k<16;k++) wbf += ws[WS_RB + p*16 + k] * Wb[k*16+g];
  float alpha = expf(fminf(ws[WS_S + p] - ws[WS_MX + dst], 0.f)) * ws[WS_ID + dst];
  float aw = alpha * wbf;
  #pragma unroll
  for(int k=0;k<25;k++){
    const float* Mr = &Ml[pl][k*28];
    float vf = 0.f;
    #pragma unroll
    for(int c=0;c<6;c++){
      float4 m4 = *(const float4*)(Mr + 4*c);
      vf += m4.x*xv_r[4*c] + m4.y*xv_r[4*c+1] + m4.z*xv_r[4*c+2] + m4.w*xv_r[4*c+3];
    }
    vf += Mr[24]*xv_r[24];
    float val = scrub(aw*vf);
    if(GATHER) ws[WS_PVF + (size_t)p*400 + k*16 + g] = val;
    else       unsafeAtomicAdd(&ws[WS_XQ + dst*400 + k*16 + g], val);
  }
}

__global__ __launch_bounds__(128) void k_aggp(const int* nbr, const float* Wb, float* ws){
  __shared__ __align__(16) float Ml[8][25*28];
  __shared__ float sh_s[8][9];
  agg_body<true>(nbr, Wb, ws, Ml, sh_s);
}

__global__ __launch_bounds__(128) void k_agg3(const int* nbr, const float* Wb, float* ws){
  __shared__ __align__(16) float Ml[8][25*28];
  __shared__ float sh_s[8][9];
  agg_body<false>(nbr, Wb, ws, Ml, sh_s);
}

// ---------------- CSR gather: agg[a] = sum over pairs of pvf (Plan A) ------
__global__ __launch_bounds__(256) void k_aggather(float* ws){
  int a = blockIdx.x*4 + (threadIdx.x >> 6);
  int lane = threadIdx.x & 63;
  const int* coff = (const int*)ws + WS_COFF;
  const int* clst = (const int*)ws + WS_CLST;
  int off0 = coff[a], n = coff[a+1] - off0;
  float acc[7] = {0,0,0,0,0,0,0};
  for(int t=0; t<n; t++){
    const float* pv = ws + WS_PVF + (size_t)clst[off0+t]*400;
    #pragma unroll
    for(int j=0;j<6;j++) acc[j] += pv[j*64 + lane];
    if(lane < 16) acc[6] += pv[384 + lane];
  }
  float* agg = ws + WS_XQ + a*400;
  #pragma unroll
  for(int j=0;j<6;j++) agg[j*64 + lane] = acc[j];
  if(lane < 16) agg[384 + lane] = acc[6];
}

// ---------------- output pdense + bias: reads XQ(agg), writes XA ----------
__global__ __launch_bounds__(256) void k_o(const float* Wo, const float* bo, float* ws){
  int tid = threadIdx.x, al = tid >> 4, g = tid & 15;
  int a = blockIdx.x*16 + al;
  const float* agg = ws + WS_XQ + a*400;
  int i = 0;
  #pragma unroll
  for(int l=0;l<5;l++){
    float wo[16];
    #pragma unroll
    for(int f2=0;f2<16;f2++) wo[f2] = Wo[(l*16+f2)*16+g];
    for(int mi=0; mi<2*l+1; mi++, i++){
      float acc = 0.f;
      #pragma unroll
      for(int f2=0;f2<16;f2++) acc += agg[i*16+f2]*wo[f2];
      if(i == 0) acc += bo[g];
      ws[WS_XA + a*400 + i*16 + g] = scrub(acc);
    }
  }
}

// ---------------- embedding residual + f32 output ----------------
__global__ void k_resout(const int* aZ, const float* emb, const float* Wemb,
                         const float* bemb, const float* ws, float* out){
  int idx = blockIdx.x*256 + threadIdx.x;
  if(idx >= NA*400) return;
  int a = idx/400, r2 = idx%400, i = r2>>4, f = r2&15;
  float v = ws[WS_XA + idx];
  if(i == 0){
    int Z = aZ[a];
    float res = bemb[f];
    #pragma unroll
    for(int e2=0;e2<32;e2++) res += emb[Z*32+e2] * Wemb[e2*16+f];
    v += res;
  }
  out[idx] = scrub(v);
}

extern "C" void kernel_launch(void* const* d_in, const int* in_sizes, int n_in,
                              void* d_out, int out_size, void* d_ws, size_t ws_size,
                              hipStream_t stream){
  (void)in_sizes; (void)n_in; (void)out_size;
  if(ws_size < (size_t)WS_BASE_END * sizeof(float)) return;
  bool plan_a = ws_size >= (size_t)WS_PLANA_END * sizeof(float);
  float* ws = (float*)d_ws;
  const int* aZ  = (const int*)d_in[0];
  const int* nbr = (const int*)d_in[1];
  const float* disp = (const float*)d_in[2];
  const float* Wrad = (const float*)d_in[3];
  const float* emb  = (const float*)d_in[4];
  const float* Wemb = (const float*)d_in[5];
  const float* bemb = (const float*)d_in[6];
  const float* W1   = (const float*)d_in[7];
  const float* W2   = (const float*)d_in[8];
  const float* W3   = (const float*)d_in[9];

  kq_Y<<<2,256,0,stream>>>(ws);
  kq_G<<<22,256,0,stream>>>(ws);
  kq_lists<<<1,64,0,stream>>>(ws);
  k_pair<<<192,256,0,stream>>>(disp, ws);
  hipMemsetAsync(ws + WS_CCNT, 0, NA*sizeof(int), stream);
  k_cnt<<<192,256,0,stream>>>(nbr, ws);
  k_scan<<<1,1024,0,stream>>>(ws);
  k_fill<<<192,256,0,stream>>>(nbr, ws);
  hipMemsetAsync(ws + WS_SUMS, 0, NA*144*sizeof(float), stream);
  hipMemsetAsync(ws + WS_CNT,  0, NA*sizeof(float), stream);
  k_td<<<3072,256,0,stream>>>(aZ, nbr, Wrad, W1, W2, W3, ws);
  k_x<<<6400,256,0,stream>>>(ws);

  for(int l=0;l<2;l++){
    const float* Wb = (const float*)d_in[10+6*l];
    const float* Wq = (const float*)d_in[11+6*l];
    const float* Wk = (const float*)d_in[12+6*l];
    const float* Wv = (const float*)d_in[13+6*l];
    const float* Wo = (const float*)d_in[14+6*l];
    const float* bo = (const float*)d_in[15+6*l];
    k_qkv<<<256,256,0,stream>>>(Wq, Wk, Wv, ws);
    k_s2<<<6144,128,0,stream>>>(nbr, Wb, ws);
    k_soft<<<1024,256,0,stream>>>(ws);
    if(plan_a){
      k_aggp<<<6144,128,0,stream>>>(nbr, Wb, ws);
      k_aggather<<<1024,256,0,stream>>>(ws);
    } else {
      hipMemsetAsync(ws + WS_XQ, 0, NA*400*sizeof(float), stream);
      k_agg3<<<6144,128,0,stream>>>(nbr, Wb, ws);
    }
    k_o<<<256,256,0,stream>>>(Wo, bo, ws);
  }
  k_resout<<<6400,256,0,stream>>>(aZ, emb, Wemb, bemb, ws, (float*)d_out);
}

// Round 6
// 535.372 us; speedup vs baseline: 1.9604x; 1.2626x over previous
//
#include <hip/hip_runtime.h>
#include <hip/hip_bf16.h>

#define NA 4096
#define NP 49152

// ---------------- ws layout (float-element offsets) ----------------
constexpr int WS_Y     = 0;                    // 512*25 quadrature sph
constexpr int WS_G     = 12800;                // 5625 Gaunt tensor
constexpr int WS_NATT  = WS_G + 5632;          // int
constexpr int WS_ATTW  = WS_NATT + 8;          // 1024 floats
constexpr int WS_ATTIJ = WS_ATTW + 1024;       // 1024 ints, sorted by k
constexpr int WS_TDOFS = WS_ATTIJ + 1024;      // 16 ints
constexpr int WS_TDW   = WS_TDOFS + 16;        // 512 floats
constexpr int WS_TDIJ  = WS_TDW + 512;         // 512 ints
constexpr int WS_AOFS  = WS_TDIJ + 512;        // 32 ints
constexpr int WS_SH    = WS_AOFS + 32;         // NP*9
constexpr int WS_RB    = WS_SH + NP*9;         // NP*16
constexpr int WS_S     = WS_RB + NP*16;        // NP scores
constexpr int WS_CCNT  = WS_S + NP;            // NA ints
constexpr int WS_COFF  = WS_CCNT + NA;         // NA+1 ints
constexpr int WS_CCUR  = WS_COFF + NA + 8;     // NA ints
constexpr int WS_CLST  = WS_CCUR + NA;         // NP ints
constexpr int WS_XA    = WS_CLST + NP;         // NA*400 x
constexpr int WS_XQ    = WS_XA + NA*400;       // NA*400 q, reused as agg
constexpr int WS_XK    = WS_XQ + NA*400;
constexpr int WS_XV    = WS_XK + NA*400;
constexpr int WS_PVF   = WS_XV + NA*400;       // NP*400 per-pair scratch (also PTD, NP*144)
constexpr long long WS_END = (long long)WS_PVF + (long long)NP*400; // ~112 MB (fits: r5 ran plan A)

__device__ const float  GLX[16] = {
  -0.98940093499164993f, -0.94457502307323258f, -0.86563120238783174f, -0.75540440835500303f,
  -0.61787624440264375f, -0.45801677765722739f, -0.28160355077925891f, -0.09501250983763744f,
   0.09501250983763744f,  0.28160355077925891f,  0.45801677765722739f,  0.61787624440264375f,
   0.75540440835500303f,  0.86563120238783174f,  0.94457502307323258f,  0.98940093499164993f };
__device__ const double GLW[16] = {
  0.02715245941175409, 0.06225352393864789, 0.09515851168249278, 0.12462897125553387,
  0.14959598881657673, 0.16915651939500254, 0.18260341504492359, 0.18945061045506850,
  0.18945061045506850, 0.18260341504492359, 0.16915651939500254, 0.14959598881657673,
  0.12462897125553387, 0.09515851168249278, 0.06225352393864789, 0.02715245941175409 };

#define PI_D 3.14159265358979323846

__device__ __forceinline__ float scrub(float v){
  if(!(v == v)) return 0.f;
  return fminf(fmaxf(v, -1e30f), 1e30f);
}

// full real spherical harmonics, lmax=4
__device__ void real_sph25(float ct, float phi, float* Y){
  float st = sqrtf(fmaxf(0.f, 1.f - ct*ct));
  float P[5][5];
  P[0][0] = 1.f;
  #pragma unroll
  for(int m=1;m<=4;m++) P[m][m] = -(2.f*m - 1.f)*st*P[m-1][m-1];
  #pragma unroll
  for(int m=0;m<4;m++) P[m+1][m] = (2.f*m + 1.f)*ct*P[m][m];
  #pragma unroll
  for(int m=0;m<=4;m++){
    #pragma unroll
    for(int l=m+2;l<=4;l++)
      P[l][m] = ((2.f*l - 1.f)*ct*P[l-1][m] - (float)(l+m-1)*P[l-2][m]) / (float)(l-m);
  }
  const double fact[9] = {1,1,2,6,24,120,720,5040,40320};
  int idx = 0;
  #pragma unroll
  for(int l=0;l<=4;l++){
    #pragma unroll
    for(int m=-l;m<=l;m++){
      int ma = (m < 0) ? -m : m;
      float Nn = (float)sqrt((2*l+1)/(4.0*PI_D)*fact[l-ma]/fact[l+ma]);
      float cs = (ma & 1) ? -1.f : 1.f;
      float v;
      if(m == 0)      v = Nn * P[l][0];
      else if(m > 0)  v = 1.4142135623730951f * Nn * cs * cosf(ma*phi) * P[l][ma];
      else            v = 1.4142135623730951f * Nn * cs * sinf(ma*phi) * P[l][ma];
      Y[idx++] = v;
    }
  }
}

__global__ void kq_Y(float* ws){
  int g = blockIdx.x*256 + threadIdx.x;
  if(g >= 512) return;
  float ct  = GLX[g >> 5];
  float phi = (float)((g & 31) * (2.0*PI_D/32.0));
  float Y[25];
  real_sph25(ct, phi, Y);
  #pragma unroll
  for(int i=0;i<25;i++) ws[WS_Y + g*25 + i] = Y[i];
}

__global__ __launch_bounds__(256) void kq_G(float* ws){
  __shared__ float Ysh[12800];
  int tid = threadIdx.x;
  for(int t=tid; t<12800; t+=256) Ysh[t] = ws[WS_Y + t];
  __syncthreads();
  int t = blockIdx.x*256 + tid;
  if(t >= 5625) return;
  int k = t % 25, j = (t/25) % 9, i = t/225;
  double acc = 0.0;
  #pragma unroll 4
  for(int g=0; g<512; g++){
    double w = GLW[g >> 5] * (2.0*PI_D/32.0);
    acc += w * (double)Ysh[g*25+i] * (double)Ysh[g*25+j] * (double)Ysh[g*25+k];
  }
  if(fabs(acc) < 1e-6) acc = 0.0;
  ws[WS_G + (i*9+j)*25 + k] = (float)acc;
}

__global__ void kq_lists(float* ws){
  __shared__ int cA[25], cT[9], oA[26], oT[10];
  int t = threadIdx.x;
  const float* G = ws + WS_G;
  if(t < 25){ int c=0; for(int i=0;i<25;i++) for(int j=0;j<9;j++) if(G[(i*9+j)*25+t] != 0.f) c++; cA[t]=c; }
  if(t < 9){  int c=0; for(int i=0;i<9;i++)  for(int j=0;j<9;j++) if(G[(i*9+j)*25+t] != 0.f) c++; cT[t]=c; }
  __syncthreads();
  if(t == 0){
    int s=0; for(int k=0;k<25;k++){ oA[k]=s; s+=cA[k]; } oA[25]=s;
    ((int*)ws)[WS_NATT] = s;
    s=0; for(int k=0;k<9;k++){ oT[k]=s; s+=cT[k]; } oT[9]=s;
  }
  __syncthreads();
  float* attw = ws + WS_ATTW; int* attij = (int*)ws + WS_ATTIJ;
  int* aofs = (int*)ws + WS_AOFS;
  if(t < 26) aofs[t] = oA[t] < 1024 ? oA[t] : 1024;
  if(t < 25){
    int pos = oA[t];
    for(int i=0;i<25;i++) for(int j=0;j<9;j++){
      float w = G[(i*9+j)*25+t];
      if(w != 0.f && pos < 1024){ attw[pos]=w; attij[pos] = i | (j<<5) | (t<<9); pos++; }
    }
  }
  float* tdw = ws + WS_TDW; int* tdij = (int*)ws + WS_TDIJ; int* tdofs = (int*)ws + WS_TDOFS;
  if(t < 9){
    int pos = oT[t];
    for(int i=0;i<9;i++) for(int j=0;j<9;j++){
      float w = G[(i*9+j)*25+t];
      if(w != 0.f && pos < 512){
        int li = (i==0)?0:(i<4)?1:2, lj = (j==0)?0:(j<4)?1:2;
        tdw[pos]=w; tdij[pos] = i | (j<<5) | (li<<10) | (lj<<12); pos++;
      }
    }
    tdofs[t] = oT[t];
    if(t == 0) tdofs[9] = oT[9];
  }
}

__global__ void k_pair(const float* disp, float* ws){
  int p = blockIdx.x*256 + threadIdx.x;
  if(p >= NP) return;
  float dx = disp[3*p], dy = disp[3*p+1], dz = disp[3*p+2];
  float r = sqrtf(dx*dx + dy*dy + dz*dz);
  float inv = 1.f / fmaxf(r, 1e-9f);
  float ux = dx*inv, uy = dy*inv, uz = dz*inv;
  float sh[9];
  sh[0] = 0.28209479177387814f;
  sh[1] = 0.4886025119029199f * uy;
  sh[2] = 0.4886025119029199f * uz;
  sh[3] = 0.4886025119029199f * ux;
  sh[4] = 1.0925484305920792f * ux*uy;
  sh[5] = 1.0925484305920792f * uy*uz;
  sh[6] = 0.31539156525252005f * (3.f*uz*uz - 1.f);
  sh[7] = 1.0925484305920792f * ux*uz;
  sh[8] = 0.5462742152960396f * (ux*ux - uy*uy);
  #pragma unroll
  for(int i=0;i<9;i++) ws[WS_SH + p*9 + i] = scrub(sh[i]);
  float mask = (r < 5.f) ? 1.f : 0.f;
  #pragma unroll
  for(int k=1;k<=16;k++){
    float x  = (float)k * r * 0.2f;
    float px = 3.14159265358979323846f * x;
    float s  = (px < 1e-6f) ? 1.f : (sinf(px)/px);
    ws[WS_RB + p*16 + (k-1)] = scrub(s * mask);
  }
}

// ---------------- CSR by dst ----------------
__global__ void k_cnt(const int* nbr, float* ws){
  int p = blockIdx.x*256 + threadIdx.x;
  if(p >= NP) return;
  atomicAdd((int*)ws + WS_CCNT + nbr[2*p], 1);
}

__global__ __launch_bounds__(1024) void k_scan(float* ws){
  __shared__ int part[1024];
  int t = threadIdx.x;
  const int* cnt = (const int*)ws + WS_CCNT;
  int v0 = cnt[4*t], v1 = cnt[4*t+1], v2 = cnt[4*t+2], v3 = cnt[4*t+3];
  part[t] = v0+v1+v2+v3;
  __syncthreads();
  for(int o=1; o<1024; o<<=1){
    int x = (t >= o) ? part[t-o] : 0;
    __syncthreads();
    part[t] += x;
    __syncthreads();
  }
  int base = (t > 0) ? part[t-1] : 0;
  int* offp = (int*)ws + WS_COFF;
  int* cur  = (int*)ws + WS_CCUR;
  offp[4*t]   = base;          cur[4*t]   = base;
  offp[4*t+1] = base+v0;       cur[4*t+1] = base+v0;
  offp[4*t+2] = base+v0+v1;    cur[4*t+2] = base+v0+v1;
  offp[4*t+3] = base+v0+v1+v2; cur[4*t+3] = base+v0+v1+v2;
  if(t == 1023) offp[4096] = part[1023];
}

__global__ void k_fill(const int* nbr, float* ws){
  int p = blockIdx.x*256 + threadIdx.x;
  if(p >= NP) return;
  int d = nbr[2*p];
  int pos = atomicAdd((int*)ws + WS_CCUR + d, 1);
  ((int*)ws)[WS_CLST + pos] = p;
}

// ---------------- TD phase: per-pair, STREAMS y to PTD (no atomics) --------
__global__ __launch_bounds__(256) void k_td(const int* aZ, const int* nbr,
    const float* Wrad, const float* W1, const float* W2,
    const float* W3, float* ws){
  __shared__ float sh_s[16][9];
  __shared__ float tp_s[16][9][16];
  int tid = threadIdx.x, pl = tid >> 4, g = tid & 15;
  int p = blockIdx.x*16 + pl;
  int src = nbr[2*p+1];
  int Zj = aZ[src];
  if(g < 9) sh_s[pl][g] = ws[WS_SH + p*9 + g];
  float rbv = ws[WS_RB + p*16 + g];
  float y0 = 0.f;
  #pragma unroll
  for(int k=0;k<16;k++){
    float rk = __shfl(rbv, k, 16);
    y0 += rk * Wrad[(Zj*16+k)*16+g];
  }
  float A1[3] = {0,0,0}, A2[3] = {0,0,0};
  #pragma unroll
  for(int fp=0;fp<16;fp++){
    float v = __shfl(y0, fp, 16);
    #pragma unroll
    for(int d=0;d<3;d++){
      A1[d] += v * W1[(d*16+fp)*16+g];
      A2[d] += v * W2[(d*16+fp)*16+g];
    }
  }
  __syncthreads();
  const float* tdw = ws + WS_TDW;
  const int* tdij  = (const int*)ws + WS_TDIJ;
  const int* tdofs = (const int*)ws + WS_TDOFS;
  #pragma unroll
  for(int k=0;k<9;k++){
    float acc = 0.f;
    int e1 = tdofs[k+1];
    for(int e=tdofs[k]; e<e1; e++){
      float w = tdw[e]; int meta = tdij[e];
      int i = meta & 31, j = (meta>>5) & 15, li = (meta>>10) & 3, lj = (meta>>12) & 3;
      float a1 = (li==0)?A1[0]:(li==1)?A1[1]:A1[2];
      float a2 = (lj==0)?A2[0]:(lj==1)?A2[1]:A2[2];
      acc += w * sh_s[pl][i] * sh_s[pl][j] * a1 * a2;
    }
    tp_s[pl][k][g] = acc;
  }
  __syncthreads();
  float* ptd = ws + WS_PVF;
  #pragma unroll
  for(int k=0;k<9;k++){
    int d = (k==0)?0:(k<4)?1:2;
    float acc = 0.f;
    #pragma unroll
    for(int f2=0;f2<16;f2++) acc += tp_s[pl][k][f2] * W3[(d*16+f2)*16+g];
    ptd[(size_t)p*144 + k*16 + g] = scrub(acc);
  }
}

// ---------------- TD gather: mean over CSR pairs, write padded XA ----------
__global__ __launch_bounds__(256) void k_tdgather(float* ws){
  int a = blockIdx.x*4 + (threadIdx.x >> 6);
  int lane = threadIdx.x & 63;
  const int* coff = (const int*)ws + WS_COFF;
  const int* clst = (const int*)ws + WS_CLST;
  int off0 = coff[a], n = coff[a+1] - off0;
  float a0 = 0.f, a1 = 0.f, a2 = 0.f;
  for(int t=0; t<n; t++){
    const float* pv = ws + WS_PVF + (size_t)clst[off0+t]*144;
    a0 += pv[lane];
    a1 += pv[64 + lane];
    if(lane < 16) a2 += pv[128 + lane];
  }
  float invn = 1.f / fmaxf((float)n, 1.f);
  float* xa = ws + WS_XA + a*400;
  xa[lane]      = scrub(a0*invn);
  xa[64 + lane] = scrub(a1*invn);
  if(lane < 16) xa[128 + lane] = scrub(a2*invn);
  #pragma unroll
  for(int j=0;j<4;j++) xa[144 + j*64 + lane] = 0.f;
}

// ---------------- per-atom Q/K/V pdense; NL l-blocks (3 for layer1) --------
template<int NL>
__global__ __launch_bounds__(256) void k_qkv(const float* Wq,
    const float* Wk, const float* Wv, float* ws){
  int tid = threadIdx.x, al = tid >> 4, g = tid & 15;
  int a = blockIdx.x*16 + al;
  const float* x = ws + WS_XA + a*400;
  int i = 0;
  #pragma unroll
  for(int l=0;l<NL;l++){
    float wq[16], wk[16], wv[16];
    #pragma unroll
    for(int f2=0;f2<16;f2++){
      wq[f2] = Wq[(l*16+f2)*16+g];
      wk[f2] = Wk[(l*16+f2)*16+g];
      wv[f2] = Wv[(l*16+f2)*16+g];
    }
    for(int mi=0; mi<2*l+1; mi++, i++){
      float q=0.f, k2=0.f, v2=0.f;
      #pragma unroll
      for(int f2=0;f2<16;f2++){
        float xv = x[i*16+f2];
        q += xv*wq[f2]; k2 += xv*wk[f2]; v2 += xv*wv[f2];
      }
      ws[WS_XQ + a*400 + i*16 + g] = q;
      ws[WS_XK + a*400 + i*16 + g] = k2;
      ws[WS_XV + a*400 + i*16 + g] = v2;
    }
  }
}

// Conflict-free M build (8 pairs x 16 lanes / 128-thr block)
#define M_BUILD() \
  do { \
    float4* M4 = (float4*)&Ml[0][0]; \
    for(int t0=tid; t0<8*25*7; t0+=128) M4[t0] = make_float4(0.f,0.f,0.f,0.f); \
    if(g < 9) sh_s[pl][g] = ws[WS_SH + p*9 + g]; \
    __syncthreads(); \
    const float* attw = ws + WS_ATTW; \
    const int* attij  = (const int*)ws + WS_ATTIJ; \
    const int* aofs   = (const int*)ws + WS_AOFS; \
    for(int kr=g; kr<25; kr+=16){ \
      float* Mrow = &Ml[pl][kr*28]; \
      int e1 = aofs[kr+1]; \
      for(int e=aofs[kr]; e<e1; e++){ \
        int meta = attij[e]; \
        Mrow[meta & 31] += attw[e] * sh_s[pl][(meta>>5) & 15]; \
      } \
    } \
    __syncthreads(); \
  } while(0)

// ---------------- MERGED attention: one M sweep feeds s AND wbf*vf ---------
// NI = count of nonzero x rows feeding this layer (9 for layer 1, 25 after).
template<int NI>
__global__ __launch_bounds__(128) void k_att(const int* nbr, const float* Wb, float* ws){
  __shared__ __align__(16) float Ml[8][25*28];
  __shared__ float sh_s[8][9];
  int tid = threadIdx.x, pl = tid >> 4, g = tid & 15;
  int p = blockIdx.x*8 + pl;
  M_BUILD();
  int dst = nbr[2*p], src = nbr[2*p+1];
  float q_r[NI], xk_r[NI], xv_r[NI];
  #pragma unroll
  for(int i=0;i<NI;i++){
    q_r[i]  = ws[WS_XQ + dst*400 + i*16 + g];
    xk_r[i] = ws[WS_XK + src*400 + i*16 + g];
    xv_r[i] = ws[WS_XV + src*400 + i*16 + g];
  }
  float rbv = ws[WS_RB + p*16 + g];
  float wbf = 0.f;
  #pragma unroll
  for(int k=0;k<16;k++) wbf += __shfl(rbv, k, 16) * Wb[k*16+g];
  constexpr int C4 = NI/4;          // 6 for 25, 2 for 9
  float* pvf = ws + WS_PVF + (size_t)p*400;
  float sacc = 0.f;
  #pragma unroll
  for(int k=0;k<25;k++){
    const float* Mr = &Ml[pl][k*28];
    float vv = 0.f, kf = 0.f;
    #pragma unroll
    for(int c=0;c<C4;c++){
      float4 m4 = *(const float4*)(Mr + 4*c);
      vv += m4.x*xv_r[4*c] + m4.y*xv_r[4*c+1] + m4.z*xv_r[4*c+2] + m4.w*xv_r[4*c+3];
      if(k < NI)
        kf += m4.x*xk_r[4*c] + m4.y*xk_r[4*c+1] + m4.z*xk_r[4*c+2] + m4.w*xk_r[4*c+3];
    }
    vv += Mr[NI-1]*xv_r[NI-1];
    if(k < NI){
      kf += Mr[NI-1]*xk_r[NI-1];
      sacc += q_r[k]*kf;
    }
    pvf[k*16 + g] = scrub(wbf*vv);
  }
  float sl = wbf * sacc;
  #pragma unroll
  for(int off=1; off<16; off<<=1) sl += __shfl_xor(sl, off, 16);
  if(g == 0) ws[WS_S + p] = scrub(sl * 0.05f);   // / sqrt(25*16)
}

// ---------------- gather: softmax stats + alpha-weighted CSR reduce --------
__global__ __launch_bounds__(256) void k_aggather(float* ws){
  int a = blockIdx.x*4 + (threadIdx.x >> 6);
  int lane = threadIdx.x & 63;
  const int* coff = (const int*)ws + WS_COFF;
  const int* clst = (const int*)ws + WS_CLST;
  int off0 = coff[a], n = coff[a+1] - off0;
  float mx = -1e30f;
  for(int t=lane; t<n; t+=64) mx = fmaxf(mx, ws[WS_S + clst[off0+t]]);
  #pragma unroll
  for(int off=1; off<64; off<<=1) mx = fmaxf(mx, __shfl_xor(mx, off));
  float den = 0.f;
  for(int t=lane; t<n; t+=64) den += expf(fminf(ws[WS_S + clst[off0+t]] - mx, 0.f));
  #pragma unroll
  for(int off=1; off<64; off<<=1) den += __shfl_xor(den, off);
  float inv_den = 1.f / (den + 1e-9f);
  float acc[7] = {0,0,0,0,0,0,0};
  for(int t=0; t<n; t++){
    int p = clst[off0+t];
    float alpha = expf(fminf(ws[WS_S + p] - mx, 0.f)) * inv_den;
    const float* pv = ws + WS_PVF + (size_t)p*400;
    #pragma unroll
    for(int j=0;j<6;j++) acc[j] += alpha * pv[j*64 + lane];
    if(lane < 16) acc[6] += alpha * pv[384 + lane];
  }
  float* agg = ws + WS_XQ + a*400;
  #pragma unroll
  for(int j=0;j<6;j++) agg[j*64 + lane] = scrub(acc[j]);
  if(lane < 16) agg[384 + lane] = scrub(acc[6]);
}

// ---------------- output pdense + bias; FINAL adds residual, writes out ----
template<bool FINAL>
__global__ __launch_bounds__(256) void k_o(const float* Wo, const float* bo,
    const int* aZ, const float* emb, const float* Wemb, const float* bemb,
    float* ws, float* out){
  int tid = threadIdx.x, al = tid >> 4, g = tid & 15;
  int a = blockIdx.x*16 + al;
  const float* agg = ws + WS_XQ + a*400;
  int i = 0;
  #pragma unroll
  for(int l=0;l<5;l++){
    float wo[16];
    #pragma unroll
    for(int f2=0;f2<16;f2++) wo[f2] = Wo[(l*16+f2)*16+g];
    for(int mi=0; mi<2*l+1; mi++, i++){
      float acc = 0.f;
      #pragma unroll
      for(int f2=0;f2<16;f2++) acc += agg[i*16+f2]*wo[f2];
      if(i == 0){
        acc += bo[g];
        if(FINAL){
          int Z = aZ[a];
          float res = bemb[g];
          #pragma unroll
          for(int e2=0;e2<32;e2++) res += emb[Z*32+e2] * Wemb[e2*16+g];
          acc += res;
        }
      }
      if(FINAL) out[a*400 + i*16 + g] = scrub(acc);
      else      ws[WS_XA + a*400 + i*16 + g] = scrub(acc);
    }
  }
}

extern "C" void kernel_launch(void* const* d_in, const int* in_sizes, int n_in,
                              void* d_out, int out_size, void* d_ws, size_t ws_size,
                              hipStream_t stream){
  (void)in_sizes; (void)n_in; (void)out_size;
  if(ws_size < (size_t)WS_END * sizeof(float)) return;  // known to fit (r5 ran plan A)
  float* ws = (float*)d_ws;
  const int* aZ  = (const int*)d_in[0];
  const int* nbr = (const int*)d_in[1];
  const float* disp = (const float*)d_in[2];
  const float* Wrad = (const float*)d_in[3];
  const float* emb  = (const float*)d_in[4];
  const float* Wemb = (const float*)d_in[5];
  const float* bemb = (const float*)d_in[6];
  const float* W1   = (const float*)d_in[7];
  const float* W2   = (const float*)d_in[8];
  const float* W3   = (const float*)d_in[9];

  kq_Y<<<2,256,0,stream>>>(ws);
  kq_G<<<22,256,0,stream>>>(ws);
  kq_lists<<<1,64,0,stream>>>(ws);
  k_pair<<<192,256,0,stream>>>(disp, ws);
  hipMemsetAsync(ws + WS_CCNT, 0, NA*sizeof(int), stream);
  k_cnt<<<192,256,0,stream>>>(nbr, ws);
  k_scan<<<1,1024,0,stream>>>(ws);
  k_fill<<<192,256,0,stream>>>(nbr, ws);
  k_td<<<3072,256,0,stream>>>(aZ, nbr, Wrad, W1, W2, W3, ws);
  k_tdgather<<<1024,256,0,stream>>>(ws);

  for(int l=0;l<2;l++){
    const float* Wb = (const float*)d_in[10+6*l];
    const float* Wq = (const float*)d_in[11+6*l];
    const float* Wk = (const float*)d_in[12+6*l];
    const float* Wv = (const float*)d_in[13+6*l];
    const float* Wo = (const float*)d_in[14+6*l];
    const float* bo = (const float*)d_in[15+6*l];
    if(l == 0){
      k_qkv<3><<<256,256,0,stream>>>(Wq, Wk, Wv, ws);
      k_att<9><<<6144,128,0,stream>>>(nbr, Wb, ws);
    } else {
      k_qkv<5><<<256,256,0,stream>>>(Wq, Wk, Wv, ws);
      k_att<25><<<6144,128,0,stream>>>(nbr, Wb, ws);
    }
    k_aggather<<<1024,256,0,stream>>>(ws);
    if(l == 0) k_o<false><<<256,256,0,stream>>>(Wo, bo, aZ, emb, Wemb, bemb, ws, nullptr);
    else       k_o<true ><<<256,256,0,stream>>>(Wo, bo, aZ, emb, Wemb, bemb, ws, (float*)d_out);
  }
}

// Round 7
// 489.672 us; speedup vs baseline: 2.1433x; 1.0933x over previous
//
#include <hip/hip_runtime.h>
#include <hip/hip_bf16.h>

#define NA 4096
#define NP 49152

typedef _Float16 f16;
typedef _Float16 h2 __attribute__((ext_vector_type(2)));
union U4H { uint4 u; f16 h[8]; h2 p[4]; };

__device__ __forceinline__ float fdot2(h2 a, h2 b, float c){
#if __has_builtin(__builtin_amdgcn_fdot2)
  return __builtin_amdgcn_fdot2(a, b, c, false);
#else
  return c + (float)a.x*(float)b.x + (float)a.y*(float)b.y;
#endif
}

// ---------------- ws layout (float-element offsets) ----------------
constexpr int WS_Y     = 0;                    // 512*25 quadrature sph
constexpr int WS_G     = 12800;                // 5625 Gaunt tensor
constexpr int WS_NATT  = WS_G + 5632;          // int
constexpr int WS_ATTW  = WS_NATT + 8;          // 1024 floats
constexpr int WS_ATTIJ = WS_ATTW + 1024;       // 1024 ints, sorted by k (i-major inside)
constexpr int WS_TDOFS = WS_ATTIJ + 1024;      // 16 ints
constexpr int WS_TDW   = WS_TDOFS + 16;        // 512 floats
constexpr int WS_TDIJ  = WS_TDW + 512;         // 512 ints
constexpr int WS_AOFS  = WS_TDIJ + 512;        // 32 ints
constexpr int WS_SH    = WS_AOFS + 32;         // NP*9
constexpr int WS_RB    = WS_SH + NP*9;         // NP*16
constexpr int WS_S     = WS_RB + NP*16;        // NP scores (sorted index)
constexpr int WS_CCNT  = WS_S + NP;            // NA ints
constexpr int WS_COFF  = WS_CCNT + NA;         // NA+1 ints
constexpr int WS_CCUR  = WS_COFF + NA + 8;     // NA ints
constexpr int WS_CLST  = WS_CCUR + NA;         // NP ints (pair ids sorted by dst)
constexpr int WS_XA    = WS_CLST + NP;         // NA*400 f32 x
constexpr int WS_XQ    = WS_XA + NA*400;       // NA*400: q (f16 transposed) then agg (f32 flat)
constexpr int WS_XK    = WS_XQ + NA*400;       // f16 transposed (800 halves/atom region)
constexpr int WS_XV    = WS_XK + NA*400;
constexpr int WS_PVF   = WS_XV + NA*400;       // f16 stream: NP*400 halves (also PTD NP*144)
constexpr long long WS_END = (long long)WS_PVF + (long long)NP*200;

__device__ const float  GLX[16] = {
  -0.98940093499164993f, -0.94457502307323258f, -0.86563120238783174f, -0.75540440835500303f,
  -0.61787624440264375f, -0.45801677765722739f, -0.28160355077925891f, -0.09501250983763744f,
   0.09501250983763744f,  0.28160355077925891f,  0.45801677765722739f,  0.61787624440264375f,
   0.75540440835500303f,  0.86563120238783174f,  0.94457502307323258f,  0.98940093499164993f };
__device__ const double GLW[16] = {
  0.02715245941175409, 0.06225352393864789, 0.09515851168249278, 0.12462897125553387,
  0.14959598881657673, 0.16915651939500254, 0.18260341504492359, 0.18945061045506850,
  0.18945061045506850, 0.18260341504492359, 0.16915651939500254, 0.14959598881657673,
  0.12462897125553387, 0.09515851168249278, 0.06225352393864789, 0.02715245941175409 };

#define PI_D 3.14159265358979323846

__device__ __forceinline__ float scrub(float v){
  if(!(v == v)) return 0.f;
  return fminf(fmaxf(v, -1e30f), 1e30f);
}

__device__ void real_sph25(float ct, float phi, float* Y){
  float st = sqrtf(fmaxf(0.f, 1.f - ct*ct));
  float P[5][5];
  P[0][0] = 1.f;
  #pragma unroll
  for(int m=1;m<=4;m++) P[m][m] = -(2.f*m - 1.f)*st*P[m-1][m-1];
  #pragma unroll
  for(int m=0;m<4;m++) P[m+1][m] = (2.f*m + 1.f)*ct*P[m][m];
  #pragma unroll
  for(int m=0;m<=4;m++){
    #pragma unroll
    for(int l=m+2;l<=4;l++)
      P[l][m] = ((2.f*l - 1.f)*ct*P[l-1][m] - (float)(l+m-1)*P[l-2][m]) / (float)(l-m);
  }
  const double fact[9] = {1,1,2,6,24,120,720,5040,40320};
  int idx = 0;
  #pragma unroll
  for(int l=0;l<=4;l++){
    #pragma unroll
    for(int m=-l;m<=l;m++){
      int ma = (m < 0) ? -m : m;
      float Nn = (float)sqrt((2*l+1)/(4.0*PI_D)*fact[l-ma]/fact[l+ma]);
      float cs = (ma & 1) ? -1.f : 1.f;
      float v;
      if(m == 0)      v = Nn * P[l][0];
      else if(m > 0)  v = 1.4142135623730951f * Nn * cs * cosf(ma*phi) * P[l][ma];
      else            v = 1.4142135623730951f * Nn * cs * sinf(ma*phi) * P[l][ma];
      Y[idx++] = v;
    }
  }
}

__global__ void kq_Y(float* ws){
  int g = blockIdx.x*256 + threadIdx.x;
  if(g >= 512) return;
  float ct  = GLX[g >> 5];
  float phi = (float)((g & 31) * (2.0*PI_D/32.0));
  float Y[25];
  real_sph25(ct, phi, Y);
  #pragma unroll
  for(int i=0;i<25;i++) ws[WS_Y + g*25 + i] = Y[i];
}

__global__ __launch_bounds__(256) void kq_G(float* ws){
  __shared__ float Ysh[12800];
  int tid = threadIdx.x;
  for(int t=tid; t<12800; t+=256) Ysh[t] = ws[WS_Y + t];
  __syncthreads();
  int t = blockIdx.x*256 + tid;
  if(t >= 5625) return;
  int k = t % 25, j = (t/25) % 9, i = t/225;
  double acc = 0.0;
  #pragma unroll 4
  for(int g=0; g<512; g++){
    double w = GLW[g >> 5] * (2.0*PI_D/32.0);
    acc += w * (double)Ysh[g*25+i] * (double)Ysh[g*25+j] * (double)Ysh[g*25+k];
  }
  if(fabs(acc) < 1e-6) acc = 0.0;
  ws[WS_G + (i*9+j)*25 + k] = (float)acc;
}

__global__ void kq_lists(float* ws){
  __shared__ int cA[25], cT[9], oA[26], oT[10];
  int t = threadIdx.x;
  const float* G = ws + WS_G;
  if(t < 25){ int c=0; for(int i=0;i<25;i++) for(int j=0;j<9;j++) if(G[(i*9+j)*25+t] != 0.f) c++; cA[t]=c; }
  if(t < 9){  int c=0; for(int i=0;i<9;i++)  for(int j=0;j<9;j++) if(G[(i*9+j)*25+t] != 0.f) c++; cT[t]=c; }
  __syncthreads();
  if(t == 0){
    int s=0; for(int k=0;k<25;k++){ oA[k]=s; s+=cA[k]; } oA[25]=s;
    ((int*)ws)[WS_NATT] = s;
    s=0; for(int k=0;k<9;k++){ oT[k]=s; s+=cT[k]; } oT[9]=s;
  }
  __syncthreads();
  float* attw = ws + WS_ATTW; int* attij = (int*)ws + WS_ATTIJ;
  int* aofs = (int*)ws + WS_AOFS;
  if(t < 26) aofs[t] = oA[t] < 1024 ? oA[t] : 1024;
  if(t < 25){
    int pos = oA[t];
    for(int i=0;i<25;i++) for(int j=0;j<9;j++){
      float w = G[(i*9+j)*25+t];
      if(w != 0.f && pos < 1024){ attw[pos]=w; attij[pos] = i | (j<<5) | (t<<9); pos++; }
    }
  }
  float* tdw = ws + WS_TDW; int* tdij = (int*)ws + WS_TDIJ; int* tdofs = (int*)ws + WS_TDOFS;
  if(t < 9){
    int pos = oT[t];
    for(int i=0;i<9;i++) for(int j=0;j<9;j++){
      float w = G[(i*9+j)*25+t];
      if(w != 0.f && pos < 512){
        int li = (i==0)?0:(i<4)?1:2, lj = (j==0)?0:(j<4)?1:2;
        tdw[pos]=w; tdij[pos] = i | (j<<5) | (li<<10) | (lj<<12); pos++;
      }
    }
    tdofs[t] = oT[t];
    if(t == 0) tdofs[9] = oT[9];
  }
}

__global__ void k_pair(const float* disp, float* ws){
  int p = blockIdx.x*256 + threadIdx.x;
  if(p >= NP) return;
  float dx = disp[3*p], dy = disp[3*p+1], dz = disp[3*p+2];
  float r = sqrtf(dx*dx + dy*dy + dz*dz);
  float inv = 1.f / fmaxf(r, 1e-9f);
  float ux = dx*inv, uy = dy*inv, uz = dz*inv;
  float sh[9];
  sh[0] = 0.28209479177387814f;
  sh[1] = 0.4886025119029199f * uy;
  sh[2] = 0.4886025119029199f * uz;
  sh[3] = 0.4886025119029199f * ux;
  sh[4] = 1.0925484305920792f * ux*uy;
  sh[5] = 1.0925484305920792f * uy*uz;
  sh[6] = 0.31539156525252005f * (3.f*uz*uz - 1.f);
  sh[7] = 1.0925484305920792f * ux*uz;
  sh[8] = 0.5462742152960396f * (ux*ux - uy*uy);
  #pragma unroll
  for(int i=0;i<9;i++) ws[WS_SH + p*9 + i] = scrub(sh[i]);
  float mask = (r < 5.f) ? 1.f : 0.f;
  #pragma unroll
  for(int k=1;k<=16;k++){
    float x  = (float)k * r * 0.2f;
    float px = 3.14159265358979323846f * x;
    float s  = (px < 1e-6f) ? 1.f : (sinf(px)/px);
    ws[WS_RB + p*16 + (k-1)] = scrub(s * mask);
  }
}

// ---------------- CSR by dst ----------------
__global__ void k_cnt(const int* nbr, float* ws){
  int p = blockIdx.x*256 + threadIdx.x;
  if(p >= NP) return;
  atomicAdd((int*)ws + WS_CCNT + nbr[2*p], 1);
}

__global__ __launch_bounds__(1024) void k_scan(float* ws){
  __shared__ int part[1024];
  int t = threadIdx.x;
  const int* cnt = (const int*)ws + WS_CCNT;
  int v0 = cnt[4*t], v1 = cnt[4*t+1], v2 = cnt[4*t+2], v3 = cnt[4*t+3];
  part[t] = v0+v1+v2+v3;
  __syncthreads();
  for(int o=1; o<1024; o<<=1){
    int x = (t >= o) ? part[t-o] : 0;
    __syncthreads();
    part[t] += x;
    __syncthreads();
  }
  int base = (t > 0) ? part[t-1] : 0;
  int* offp = (int*)ws + WS_COFF;
  int* cur  = (int*)ws + WS_CCUR;
  offp[4*t]   = base;          cur[4*t]   = base;
  offp[4*t+1] = base+v0;       cur[4*t+1] = base+v0;
  offp[4*t+2] = base+v0+v1;    cur[4*t+2] = base+v0+v1;
  offp[4*t+3] = base+v0+v1+v2; cur[4*t+3] = base+v0+v1+v2;
  if(t == 1023) offp[4096] = part[1023];
}

__global__ void k_fill(const int* nbr, float* ws){
  int p = blockIdx.x*256 + threadIdx.x;
  if(p >= NP) return;
  int d = nbr[2*p];
  int pos = atomicAdd((int*)ws + WS_CCUR + d, 1);
  ((int*)ws)[WS_CLST + pos] = p;
}

// ---------------- TD phase: per-pair, streams f16 ptd at SORTED index ------
__global__ __launch_bounds__(256) void k_td(const int* aZ, const int* nbr,
    const float* Wrad, const float* W1, const float* W2,
    const float* W3, float* ws){
  __shared__ float sh_s[16][9];
  __shared__ float tp_s[16][9][16];
  int tid = threadIdx.x, pl = tid >> 4, g = tid & 15;
  int sp = blockIdx.x*16 + pl;
  int p = ((const int*)ws)[WS_CLST + sp];
  int src = nbr[2*p+1];
  int Zj = aZ[src];
  if(g < 9) sh_s[pl][g] = ws[WS_SH + p*9 + g];
  float rbv = ws[WS_RB + p*16 + g];
  float y0 = 0.f;
  #pragma unroll
  for(int k=0;k<16;k++){
    float rk = __shfl(rbv, k, 16);
    y0 += rk * Wrad[(Zj*16+k)*16+g];
  }
  float A1[3] = {0,0,0}, A2[3] = {0,0,0};
  #pragma unroll
  for(int fp=0;fp<16;fp++){
    float v = __shfl(y0, fp, 16);
    #pragma unroll
    for(int d=0;d<3;d++){
      A1[d] += v * W1[(d*16+fp)*16+g];
      A2[d] += v * W2[(d*16+fp)*16+g];
    }
  }
  __syncthreads();
  const float* tdw = ws + WS_TDW;
  const int* tdij  = (const int*)ws + WS_TDIJ;
  const int* tdofs = (const int*)ws + WS_TDOFS;
  #pragma unroll
  for(int k=0;k<9;k++){
    float acc = 0.f;
    int e1 = tdofs[k+1];
    for(int e=tdofs[k]; e<e1; e++){
      float w = tdw[e]; int meta = tdij[e];
      int i = meta & 31, j = (meta>>5) & 15, li = (meta>>10) & 3, lj = (meta>>12) & 3;
      float a1 = (li==0)?A1[0]:(li==1)?A1[1]:A1[2];
      float a2 = (lj==0)?A2[0]:(lj==1)?A2[1]:A2[2];
      acc += w * sh_s[pl][i] * sh_s[pl][j] * a1 * a2;
    }
    tp_s[pl][k][g] = acc;
  }
  __syncthreads();
  f16* ptd = (f16*)(ws + WS_PVF);
  #pragma unroll
  for(int k=0;k<9;k++){
    int d = (k==0)?0:(k<4)?1:2;
    float acc = 0.f;
    #pragma unroll
    for(int f2=0;f2<16;f2++) acc += tp_s[pl][k][f2] * W3[(d*16+f2)*16+g];
    ptd[(size_t)sp*144 + k*16 + g] = (f16)scrub(acc);
  }
}

// ---------------- TD gather: mean over contiguous f16 rows -----------------
__global__ __launch_bounds__(256) void k_tdgather(float* ws){
  int a = blockIdx.x*4 + (threadIdx.x >> 6);
  int lane = threadIdx.x & 63;
  const int* coff = (const int*)ws + WS_COFF;
  int off0 = coff[a], n = coff[a+1] - off0;
  float acc[8] = {0,0,0,0,0,0,0,0};
  const f16* base = (const f16*)(ws + WS_PVF);
  for(int t=0; t<n; t++){
    if(lane < 18){
      U4H u; u.u = *(const uint4*)(base + (size_t)(off0+t)*144 + lane*8);
      #pragma unroll
      for(int j=0;j<8;j++) acc[j] += (float)u.h[j];
    }
  }
  float invn = 1.f / fmaxf((float)n, 1.f);
  float* xa = ws + WS_XA + a*400;
  if(lane < 18){
    #pragma unroll
    for(int j=0;j<8;j++) xa[lane*8 + j] = scrub(acc[j]*invn);
  }
  #pragma unroll
  for(int j=0;j<4;j++) xa[144 + j*64 + lane] = 0.f;
}

// ---------------- Q/K/V pdense -> f16 transposed (stride 32 halves) --------
template<int NL>
__global__ __launch_bounds__(256) void k_qkv(const float* Wq,
    const float* Wk, const float* Wv, float* ws){
  int tid = threadIdx.x, al = tid >> 4, g = tid & 15;
  int a = blockIdx.x*16 + al;
  const float* x = ws + WS_XA + a*400;
  constexpr int NR = NL*NL;
  float q_r[NR], k_r[NR], v_r[NR];
  int i = 0;
  #pragma unroll
  for(int l=0;l<NL;l++){
    float wq[16], wk[16], wv[16];
    #pragma unroll
    for(int f2=0;f2<16;f2++){
      wq[f2] = Wq[(l*16+f2)*16+g];
      wk[f2] = Wk[(l*16+f2)*16+g];
      wv[f2] = Wv[(l*16+f2)*16+g];
    }
    for(int mi=0; mi<2*l+1; mi++, i++){
      float q=0.f, k2=0.f, v2=0.f;
      #pragma unroll
      for(int f2=0;f2<16;f2++){
        float xv = x[i*16+f2];
        q += xv*wq[f2]; k2 += xv*wk[f2]; v2 += xv*wv[f2];
      }
      q_r[i]=q; k_r[i]=k2; v_r[i]=v2;
    }
  }
  f16* qt = (f16*)(ws + WS_XQ) + (size_t)a*800 + g*32;
  f16* kt = (f16*)(ws + WS_XK) + (size_t)a*800 + g*32;
  f16* vt = (f16*)(ws + WS_XV) + (size_t)a*800 + g*32;
  #pragma unroll
  for(int c=0;c<NR/8;c++){
    U4H uq, uk, uv;
    #pragma unroll
    for(int j=0;j<4;j++){
      h2 tq, tk, tv;
      tq.x=(f16)q_r[c*8+2*j]; tq.y=(f16)q_r[c*8+2*j+1];
      tk.x=(f16)k_r[c*8+2*j]; tk.y=(f16)k_r[c*8+2*j+1];
      tv.x=(f16)v_r[c*8+2*j]; tv.y=(f16)v_r[c*8+2*j+1];
      uq.p[j]=tq; uk.p[j]=tk; uv.p[j]=tv;
    }
    *(uint4*)(qt + c*8) = uq.u;
    *(uint4*)(kt + c*8) = uk.u;
    *(uint4*)(vt + c*8) = uv.u;
  }
  qt[NR-1] = (f16)q_r[NR-1];
  kt[NR-1] = (f16)k_r[NR-1];
  vt[NR-1] = (f16)v_r[NR-1];
}

// ---------------- merged attention, f16 M in LDS, dot2 sweep ---------------
// NI = nonzero x rows (9 layer1, 25 layer2). Processes SORTED pair sp.
template<int NI>
__global__ __launch_bounds__(128) void k_att(const int* nbr, const float* Wb, float* ws){
  __shared__ __align__(16) f16 Ml[8][25*32];
  __shared__ float sh_s[8][9];
  constexpr int NPAIR = NI/2;        // 12 or 4
  constexpr int TAIL  = NI-1;        // 24 or 8
  int tid = threadIdx.x, pl = tid >> 4, g = tid & 15;
  int sp = blockIdx.x*8 + pl;
  int p = ((const int*)ws)[WS_CLST + sp];
  // zero M (8*25*32 halves = 800 uint4)
  {
    uint4 z; z.x=0; z.y=0; z.z=0; z.w=0;
    uint4* Mz = (uint4*)&Ml[0][0];
    for(int t0=tid; t0<800; t0+=128) Mz[t0] = z;
  }
  if(g < 9) sh_s[pl][g] = ws[WS_SH + p*9 + g];
  __syncthreads();
  // run-length f16 M build: entries per row k sorted by i
  {
    const float* attw = ws + WS_ATTW;
    const int* attij  = (const int*)ws + WS_ATTIJ;
    const int* aofs   = (const int*)ws + WS_AOFS;
    for(int kr=g; kr<25; kr+=16){
      f16* Mrow = &Ml[pl][kr*32];
      int e = aofs[kr], e1 = aofs[kr+1];
      int meta = attij[e];
      int curi = meta & 31;
      float cur = 0.f;
      for(; e<e1; e++){
        meta = attij[e];
        int i2 = meta & 31;
        if(i2 != curi){ Mrow[curi] = (f16)cur; cur = 0.f; curi = i2; }
        cur += attw[e] * sh_s[pl][(meta>>5) & 15];
      }
      Mrow[curi] = (f16)cur;
    }
  }
  __syncthreads();
  int dst = nbr[2*p], src = nbr[2*p+1];
  // q (f32 from f16 transposed row)
  float q_r[NI];
  {
    const f16* qt = (const f16*)(ws + WS_XQ) + (size_t)dst*800 + g*32;
    #pragma unroll
    for(int c=0;c<NPAIR/4;c++){
      U4H u; u.u = *(const uint4*)(qt + c*8);
      #pragma unroll
      for(int j=0;j<8;j++) q_r[c*8+j] = (float)u.h[j];
    }
    q_r[TAIL] = (float)qt[TAIL];
  }
  // k,v packed half2
  h2 xk2[NPAIR], xv2[NPAIR];
  float xkT, xvT;
  {
    const f16* kt = (const f16*)(ws + WS_XK) + (size_t)src*800 + g*32;
    const f16* vt = (const f16*)(ws + WS_XV) + (size_t)src*800 + g*32;
    #pragma unroll
    for(int c=0;c<NPAIR/4;c++){
      U4H uk; uk.u = *(const uint4*)(kt + c*8);
      U4H uv; uv.u = *(const uint4*)(vt + c*8);
      #pragma unroll
      for(int j=0;j<4;j++){ xk2[c*4+j] = uk.p[j]; xv2[c*4+j] = uv.p[j]; }
    }
    xkT = (float)kt[TAIL];
    xvT = (float)vt[TAIL];
  }
  float rbv = ws[WS_RB + p*16 + g];
  float wbf = 0.f;
  #pragma unroll
  for(int k=0;k<16;k++) wbf += __shfl(rbv, k, 16) * Wb[k*16+g];
  f16* pvf = (f16*)(ws + WS_PVF) + (size_t)sp*400;
  float sacc = 0.f;
  #pragma unroll
  for(int k=0;k<25;k++){
    const h2* M2 = (const h2*)&Ml[pl][k*32];
    float mT = (float)Ml[pl][k*32 + TAIL];
    float vv = 0.f;
    #pragma unroll
    for(int c=0;c<NPAIR;c++) vv = fdot2(M2[c], xv2[c], vv);
    vv += mT * xvT;
    if(k < NI){
      float kf = 0.f;
      #pragma unroll
      for(int c=0;c<NPAIR;c++) kf = fdot2(M2[c], xk2[c], kf);
      kf += mT * xkT;
      sacc += q_r[k]*kf;
    }
    pvf[k*16 + g] = (f16)scrub(wbf*vv);
  }
  float sl = wbf * sacc;
  #pragma unroll
  for(int off=1; off<16; off<<=1) sl += __shfl_xor(sl, off, 16);
  if(g == 0) ws[WS_S + sp] = scrub(sl * 0.05f);   // / sqrt(25*16)
}

// ---------------- gather: softmax + alpha-weighted contiguous reduce -------
__global__ __launch_bounds__(256) void k_aggather(float* ws){
  int a = blockIdx.x*4 + (threadIdx.x >> 6);
  int lane = threadIdx.x & 63;
  const int* coff = (const int*)ws + WS_COFF;
  int off0 = coff[a], n = coff[a+1] - off0;
  float mx = -1e30f;
  for(int t=lane; t<n; t+=64) mx = fmaxf(mx, ws[WS_S + off0 + t]);
  #pragma unroll
  for(int off=1; off<64; off<<=1) mx = fmaxf(mx, __shfl_xor(mx, off));
  float den = 0.f;
  for(int t=lane; t<n; t+=64) den += expf(fminf(ws[WS_S + off0 + t] - mx, 0.f));
  #pragma unroll
  for(int off=1; off<64; off<<=1) den += __shfl_xor(den, off);
  float inv_den = 1.f / (den + 1e-9f);
  float acc[8] = {0,0,0,0,0,0,0,0};
  const f16* base = (const f16*)(ws + WS_PVF);
  for(int t=0; t<n; t++){
    float alpha = expf(fminf(ws[WS_S + off0 + t] - mx, 0.f)) * inv_den;
    if(lane < 50){
      U4H u; u.u = *(const uint4*)(base + (size_t)(off0+t)*400 + lane*8);
      #pragma unroll
      for(int j=0;j<8;j++) acc[j] += alpha * (float)u.h[j];
    }
  }
  if(lane < 50){
    float* agg = ws + WS_XQ + a*400 + lane*8;
    #pragma unroll
    for(int j=0;j<8;j++) agg[j] = scrub(acc[j]);
  }
}

// ---------------- output pdense + bias; FINAL adds residual ----------------
template<bool FINAL>
__global__ __launch_bounds__(256) void k_o(const float* Wo, const float* bo,
    const int* aZ, const float* emb, const float* Wemb, const float* bemb,
    float* ws, float* out){
  int tid = threadIdx.x, al = tid >> 4, g = tid & 15;
  int a = blockIdx.x*16 + al;
  const float* agg = ws + WS_XQ + a*400;
  int i = 0;
  #pragma unroll
  for(int l=0;l<5;l++){
    float wo[16];
    #pragma unroll
    for(int f2=0;f2<16;f2++) wo[f2] = Wo[(l*16+f2)*16+g];
    for(int mi=0; mi<2*l+1; mi++, i++){
      float acc = 0.f;
      #pragma unroll
      for(int f2=0;f2<16;f2++) acc += agg[i*16+f2]*wo[f2];
      if(i == 0){
        acc += bo[g];
        if(FINAL){
          int Z = aZ[a];
          float res = bemb[g];
          #pragma unroll
          for(int e2=0;e2<32;e2++) res += emb[Z*32+e2] * Wemb[e2*16+g];
          acc += res;
        }
      }
      if(FINAL) out[a*400 + i*16 + g] = scrub(acc);
      else      ws[WS_XA + a*400 + i*16 + g] = scrub(acc);
    }
  }
}

extern "C" void kernel_launch(void* const* d_in, const int* in_sizes, int n_in,
                              void* d_out, int out_size, void* d_ws, size_t ws_size,
                              hipStream_t stream){
  (void)in_sizes; (void)n_in; (void)out_size;
  if(ws_size < (size_t)WS_END * sizeof(float)) return;
  float* ws = (float*)d_ws;
  const int* aZ  = (const int*)d_in[0];
  const int* nbr = (const int*)d_in[1];
  const float* disp = (const float*)d_in[2];
  const float* Wrad = (const float*)d_in[3];
  const float* emb  = (const float*)d_in[4];
  const float* Wemb = (const float*)d_in[5];
  const float* bemb = (const float*)d_in[6];
  const float* W1   = (const float*)d_in[7];
  const float* W2   = (const float*)d_in[8];
  const float* W3   = (const float*)d_in[9];

  kq_Y<<<2,256,0,stream>>>(ws);
  kq_G<<<22,256,0,stream>>>(ws);
  kq_lists<<<1,64,0,stream>>>(ws);
  k_pair<<<192,256,0,stream>>>(disp, ws);
  hipMemsetAsync(ws + WS_CCNT, 0, NA*sizeof(int), stream);
  k_cnt<<<192,256,0,stream>>>(nbr, ws);
  k_scan<<<1,1024,0,stream>>>(ws);
  k_fill<<<192,256,0,stream>>>(nbr, ws);
  k_td<<<3072,256,0,stream>>>(aZ, nbr, Wrad, W1, W2, W3, ws);
  k_tdgather<<<1024,256,0,stream>>>(ws);

  for(int l=0;l<2;l++){
    const float* Wb = (const float*)d_in[10+6*l];
    const float* Wq = (const float*)d_in[11+6*l];
    const float* Wk = (const float*)d_in[12+6*l];
    const float* Wv = (const float*)d_in[13+6*l];
    const float* Wo = (const float*)d_in[14+6*l];
    const float* bo = (const float*)d_in[15+6*l];
    if(l == 0){
      k_qkv<3><<<256,256,0,stream>>>(Wq, Wk, Wv, ws);
      k_att<9><<<6144,128,0,stream>>>(nbr, Wb, ws);
    } else {
      k_qkv<5><<<256,256,0,stream>>>(Wq, Wk, Wv, ws);
      k_att<25><<<6144,128,0,stream>>>(nbr, Wb, ws);
    }
    k_aggather<<<1024,256,0,stream>>>(ws);
    if(l == 0) k_o<false><<<256,256,0,stream>>>(Wo, bo, aZ, emb, Wemb, bemb, ws, nullptr);
    else       k_o<true ><<<256,256,0,stream>>>(Wo, bo, aZ, emb, Wemb, bemb, ws, (float*)d_out);
  }
}